// Round 4
// baseline (5132.657 us; speedup 1.0000x reference)
//
#include <hip/hip_runtime.h>
#include <stdint.h>

#define B_ 8
#define T_ 2048
#define D_ 1024
#define H_ 4
#define DK_ 256
#define DV_ 256
#define NH_ 2
#define I_ 2816
#define EPS_ 1e-6f

typedef __attribute__((ext_vector_type(4))) short short4v;
typedef __attribute__((ext_vector_type(8))) short bf16x8;
typedef __attribute__((ext_vector_type(4))) float f32x4;
typedef unsigned short ushort_t;

__device__ __forceinline__ unsigned short f2bf(float f) {
    union { float f; unsigned int u; } c; c.f = f;
    unsigned int r = c.u + 0x7FFFu + ((c.u >> 16) & 1u);
    return (unsigned short)(r >> 16);
}
__device__ __forceinline__ float bf2f(unsigned short s) {
    union { unsigned int u; float f; } c; c.u = ((unsigned int)s) << 16;
    return c.f;
}
__device__ __forceinline__ short4v pack4(float4 v) {
    short4v r;
    r.x = (short)f2bf(v.x); r.y = (short)f2bf(v.y);
    r.z = (short)f2bf(v.z); r.w = (short)f2bf(v.w);
    return r;
}
__device__ __forceinline__ float4 cvt4(short4v s) {
    float4 r;
    r.x = bf2f((unsigned short)s.x); r.y = bf2f((unsigned short)s.y);
    r.z = bf2f((unsigned short)s.z); r.w = bf2f((unsigned short)s.w);
    return r;
}
__device__ __forceinline__ float sigmoidf_(float x) { return 1.f / (1.f + __expf(-x)); }
__device__ __forceinline__ float siluf_(float x)    { return x / (1.f + __expf(-x)); }

// async global->LDS, 16 bytes per lane; LDS dest = wave-uniform base + lane*16
__device__ __forceinline__ void gll16(const ushort_t* g, ushort_t* l) {
    __builtin_amdgcn_global_load_lds(
        (const __attribute__((address_space(1))) uint32_t*)g,
        (__attribute__((address_space(3))) uint32_t*)l, 16, 0, 0);
}

// ---------------------------------------------------------------------------
// bf16 MFMA GEMM (m97 structure): acc = A[M,K] @ W[N,K]^T
// EPI 0: Cb = bf16(acc)
// EPI 1: Cf = acc + e0f[idx]   (f32 residual out; e0f may alias Cf, same idx)
// EPI 2: Cf = gate-blend f32: g = sigmoid(acc + e2f[b,col]);
//             Cf = g*e0f[idx] + (1-g)*e1f[b,col]
// 128x128 tile, BK=32, 256 threads (4 waves, each 64x64 via 4x4 mfma_16x16x32)
// ---------------------------------------------------------------------------
template<int EPI>
__global__ __launch_bounds__(256)
void gemm_bf16(const ushort_t* __restrict__ A, int lda,
               const ushort_t* __restrict__ W, int ldw,
               float* __restrict__ Cf, ushort_t* __restrict__ Cb,
               int M, int N, int K,
               const float* __restrict__ e0f,
               const float* __restrict__ e1f,
               const float* __restrict__ e2f)
{
    __shared__ ushort_t As[128 * 32];
    __shared__ ushort_t Bs[128 * 32];
    const int tid = threadIdx.x;
    const int m0 = blockIdx.y * 128;
    const int n0 = blockIdx.x * 128;
    const int lane = tid & 63;
    const int wv = tid >> 6;
    const int wm = (wv >> 1) * 64, wn = (wv & 1) * 64;
    const int lr = lane & 15, lk = lane >> 4;
    const int srow = lane >> 2;        // 0..15 within 16-row chunk
    const int scol = (lane & 3) * 8;   // bf16 col: 0,8,16,24

    f32x4 acc[4][4];
#pragma unroll
    for (int i = 0; i < 4; i++)
#pragma unroll
        for (int j = 0; j < 4; j++) acc[i][j] = (f32x4){0.f, 0.f, 0.f, 0.f};

    const ushort_t* Ab = A + (size_t)m0 * lda;
    const ushort_t* Wb = W + (size_t)n0 * ldw;

    for (int k0 = 0; k0 < K; k0 += 32) {
#pragma unroll
        for (int i = 0; i < 2; i++) {
            const int c = wv * 2 + i;
            const int row = c * 16 + srow;
            gll16(Ab + (size_t)row * lda + k0 + scol, &As[c * 512]);
            gll16(Wb + (size_t)row * ldw + k0 + scol, &Bs[c * 512]);
        }
        __syncthreads();
        bf16x8 af[4], bq[4];
#pragma unroll
        for (int mi = 0; mi < 4; mi++)
            af[mi] = *reinterpret_cast<const bf16x8*>(&As[(wm + mi * 16 + lr) * 32 + lk * 8]);
#pragma unroll
        for (int ni = 0; ni < 4; ni++)
            bq[ni] = *reinterpret_cast<const bf16x8*>(&Bs[(wn + ni * 16 + lr) * 32 + lk * 8]);
#pragma unroll
        for (int mi = 0; mi < 4; mi++)
#pragma unroll
            for (int ni = 0; ni < 4; ni++)
                acc[mi][ni] = __builtin_amdgcn_mfma_f32_16x16x32_bf16(af[mi], bq[ni], acc[mi][ni], 0, 0, 0);
        __syncthreads();
    }

#pragma unroll
    for (int mi = 0; mi < 4; mi++) {
#pragma unroll
        for (int ni = 0; ni < 4; ni++) {
            const int col = n0 + wn + ni * 16 + lr;
#pragma unroll
            for (int rr = 0; rr < 4; rr++) {
                const int row = m0 + wm + mi * 16 + lk * 4 + rr;
                const size_t idx = (size_t)row * N + col;
                const float val = acc[mi][ni][rr];
                if (EPI == 0) {
                    Cb[idx] = f2bf(val);
                } else if (EPI == 1) {
                    Cf[idx] = val + e0f[idx];
                } else {
                    const int b = row >> 11;  // row / T_
                    const float gate = sigmoidf_(val + e2f[b * D_ + col]);
                    Cf[idx] = gate * e0f[idx] + (1.f - gate) * e1f[b * D_ + col];
                }
            }
        }
    }
}

// fp32 -> bf16 (float4 per thread)
__global__ __launch_bounds__(256)
void tobf16_kernel(const float* __restrict__ in, ushort_t* __restrict__ out)
{
    const size_t i = (size_t)blockIdx.x * 256 + threadIdx.x;
    const float4 v = reinterpret_cast<const float4*>(in)[i];
    *reinterpret_cast<short4v*>(&out[i * 4]) = pack4(v);
}

// es[b,j] = prev[b,:] . state_proj_w[j,:]  (one wave per output)
__global__ __launch_bounds__(256)
void es_kernel(const float* __restrict__ prev, const float* __restrict__ spw,
               float* __restrict__ es)
{
    const int out = blockIdx.x * 4 + (threadIdx.x >> 6);
    const int lane = threadIdx.x & 63;
    const int b = out >> 10, j = out & 1023;
    const float4* pr = reinterpret_cast<const float4*>(prev + (size_t)b * D_);
    const float4* wr = reinterpret_cast<const float4*>(spw + (size_t)j * D_);
    float acc = 0.f;
#pragma unroll
    for (int p = 0; p < 4; p++) {
        float4 a = pr[lane + 64 * p], w = wr[lane + 64 * p];
        acc += a.x * w.x + a.y * w.y + a.z * w.z + a.w * w.w;
    }
#pragma unroll
    for (int m = 1; m < 64; m <<= 1) acc += __shfl_xor(acc, m);
    if (lane == 0) es[out] = acc;
}

// esg[b,d] = es[b,:] . state_gate_w[d, D:2D] + state_gate_b[d]
__global__ __launch_bounds__(256)
void esg_kernel(const float* __restrict__ es, const float* __restrict__ sgw,
                const float* __restrict__ sgb, float* __restrict__ esg)
{
    const int out = blockIdx.x * 4 + (threadIdx.x >> 6);
    const int lane = threadIdx.x & 63;
    const int b = out >> 10, d = out & 1023;
    const float4* er = reinterpret_cast<const float4*>(es + (size_t)b * D_);
    const float4* wr = reinterpret_cast<const float4*>(sgw + (size_t)d * (2 * D_) + D_);
    float acc = 0.f;
#pragma unroll
    for (int p = 0; p < 4; p++) {
        float4 a = er[lane + 64 * p], w = wr[lane + 64 * p];
        acc += a.x * w.x + a.y * w.y + a.z * w.z + a.w * w.w;
    }
#pragma unroll
    for (int m = 1; m < 64; m <<= 1) acc += __shfl_xor(acc, m);
    if (lane == 0) esg[out] = acc + sgb[d];
}

// RMSNorm rows of 1024, f32 in -> bf16 out
__global__ __launch_bounds__(256)
void rmsnorm_bf16_kernel(const float* __restrict__ x, const float* __restrict__ w,
                         ushort_t* __restrict__ y)
{
    const int row = blockIdx.x;
    const int tid = threadIdx.x;
    const float4 v = reinterpret_cast<const float4*>(x + (size_t)row * D_)[tid];
    float ss = v.x * v.x + v.y * v.y + v.z * v.z + v.w * v.w;
#pragma unroll
    for (int m = 1; m < 64; m <<= 1) ss += __shfl_xor(ss, m);
    __shared__ float red[4];
    if ((tid & 63) == 0) red[tid >> 6] = ss;
    __syncthreads();
    ss = red[0] + red[1] + red[2] + red[3];
    const float rs = rsqrtf(ss * (1.f / 1024.f) + EPS_);
    const float4 wv = reinterpret_cast<const float4*>(w)[tid];
    float4 r;
    r.x = v.x * rs * wv.x; r.y = v.y * rs * wv.y;
    r.z = v.z * rs * wv.z; r.w = v.w * rs * wv.w;
    *reinterpret_cast<short4v*>(&y[(size_t)row * D_ + tid * 4]) = pack4(r);
}

// per-head RMSNorm rows of 256, bf16 in -> bf16 out (one wave per row)
__global__ __launch_bounds__(256)
void onorm_bf16_kernel(const ushort_t* __restrict__ x, const float* __restrict__ w,
                       ushort_t* __restrict__ y)
{
    const int row = blockIdx.x * 4 + (threadIdx.x >> 6);
    const int lane = threadIdx.x & 63;
    const float4 v = cvt4(reinterpret_cast<const short4v*>(x + (size_t)row * 256)[lane]);
    float ss = v.x * v.x + v.y * v.y + v.z * v.z + v.w * v.w;
#pragma unroll
    for (int m = 1; m < 64; m <<= 1) ss += __shfl_xor(ss, m);
    const float rs = rsqrtf(ss * (1.f / 256.f) + EPS_);
    const float4 wv = reinterpret_cast<const float4*>(w)[lane];
    float4 r;
    r.x = v.x * rs * wv.x; r.y = v.y * rs * wv.y;
    r.z = v.z * rs * wv.z; r.w = v.w * rs * wv.w;
    *reinterpret_cast<short4v*>(&y[(size_t)row * 256 + lane * 4]) = pack4(r);
}

// l2 normalize rows of 256 in-place, bf16 (one wave per row)
__global__ __launch_bounds__(256)
void l2n_kernel(ushort_t* __restrict__ x)
{
    const int row = blockIdx.x * 4 + (threadIdx.x >> 6);
    const int lane = threadIdx.x & 63;
    short4v* xr = reinterpret_cast<short4v*>(x + (size_t)row * 256);
    float4 v = cvt4(xr[lane]);
    float ss = v.x * v.x + v.y * v.y + v.z * v.z + v.w * v.w;
#pragma unroll
    for (int m = 1; m < 64; m <<= 1) ss += __shfl_xor(ss, m);
    const float rs = rsqrtf(ss + EPS_);
    v.x *= rs; v.y *= rs; v.z *= rs; v.w *= rs;
    xr[lane] = pack4(v);
}

// causal depthwise conv (K=4) + SiLU, bf16 in/out, weights [C,4] f32.
// input rows of inC4 short4v; output rows of outC4 short4v at outOff4;
// conv-weight channel offset chOff4 (in float4 rows).
__global__ __launch_bounds__(256)
void conv_silu_kernel(const ushort_t* __restrict__ x, const float* __restrict__ w,
                      ushort_t* __restrict__ y, int inC4, int outC4, int outOff4,
                      int chOff4)
{
    const size_t gid = (size_t)blockIdx.x * 256 + threadIdx.x;
    const int c4 = (int)(gid % inC4);
    const size_t bt = gid / inC4;
    const int t = (int)(bt & (T_ - 1));
    const short4v* xr = reinterpret_cast<const short4v*>(x) + bt * inC4 + c4;
    const float4* wr = reinterpret_cast<const float4*>(w) + chOff4 + (size_t)c4 * 4;
    const float4 w0 = wr[0], w1 = wr[1], w2 = wr[2], w3 = wr[3];
    const float4 z = {0.f, 0.f, 0.f, 0.f};
    const float4 x3 = cvt4(xr[0]);
    const float4 x2v = (t >= 1) ? cvt4(xr[-(ptrdiff_t)inC4]) : z;
    const float4 x1v = (t >= 2) ? cvt4(xr[-2 * (ptrdiff_t)inC4]) : z;
    const float4 x0v = (t >= 3) ? cvt4(xr[-3 * (ptrdiff_t)inC4]) : z;
    float4 a;
    a.x = x0v.x * w0.x + x1v.x * w0.y + x2v.x * w0.z + x3.x * w0.w;
    a.y = x0v.y * w1.x + x1v.y * w1.y + x2v.y * w1.z + x3.y * w1.w;
    a.z = x0v.z * w2.x + x1v.z * w2.y + x2v.z * w2.z + x3.z * w2.w;
    a.w = x0v.w * w3.x + x1v.w * w3.y + x2v.w * w3.z + x3.w * w3.w;
    float4 r;
    r.x = siluf_(a.x); r.y = siluf_(a.y); r.z = siluf_(a.z); r.w = siluf_(a.w);
    reinterpret_cast<short4v*>(y)[bt * outC4 + outOff4 + c4] = pack4(r);
}

// beta/g projections (N=12) from bf16 h
__global__ __launch_bounds__(256)
void proj_ba_kernel(const ushort_t* __restrict__ hb, const float* __restrict__ bw,
                    const float* __restrict__ aw, const float* __restrict__ Alog,
                    const float* __restrict__ dtb,
                    float* __restrict__ beta, float* __restrict__ g)
{
    const int row = blockIdx.x;
    const int wv = threadIdx.x >> 6, lane = threadIdx.x & 63;
    const ushort_t* hr = hb + (size_t)row * D_;
#pragma unroll
    for (int s = 0; s < 3; s++) {
        const int o = wv * 3 + s;
        const float* wrow = (o < 8) ? (bw + (size_t)o * D_) : (aw + (size_t)(o - 8) * D_);
        const float4* wr4 = reinterpret_cast<const float4*>(wrow);
        float acc = 0.f;
#pragma unroll
        for (int p = 0; p < 2; p++) {
            const int gg = lane + 64 * p;
            const bf16x8 hv = *reinterpret_cast<const bf16x8*>(&hr[gg * 8]);
            const float4 wa = wr4[gg * 2], wb2 = wr4[gg * 2 + 1];
            acc += bf2f((unsigned short)hv[0]) * wa.x + bf2f((unsigned short)hv[1]) * wa.y
                 + bf2f((unsigned short)hv[2]) * wa.z + bf2f((unsigned short)hv[3]) * wa.w
                 + bf2f((unsigned short)hv[4]) * wb2.x + bf2f((unsigned short)hv[5]) * wb2.y
                 + bf2f((unsigned short)hv[6]) * wb2.z + bf2f((unsigned short)hv[7]) * wb2.w;
        }
#pragma unroll
        for (int m = 1; m < 64; m <<= 1) acc += __shfl_xor(acc, m);
        if (lane == 0) {
            if (o < 8) {
                beta[(size_t)row * 8 + o] = 2.f * sigmoidf_(acc);
            } else {
                const int hh = o - 8;
                const float xg = acc + dtb[hh];
                const float sp = (xg > 20.f) ? xg : log1pf(expf(xg));
                g[(size_t)row * 4 + hh] = -expf(Alog[hh]) * sp;
            }
        }
    }
}

// ---------------------------------------------------------------------------
// sequential gated delta-product scan (bf16 q/k/v, f32 state).
// grid = B*H*(DV/16) = 512 blocks, 128 threads.
// thread (kk = tid&7, dvl = tid>>3) owns S[kk*32+j][dv0+dvl], j=0..31.
// k/q staged in LDS f32 with 36-stride swizzle (conflict-free b128 reads).
// ---------------------------------------------------------------------------
__global__ __launch_bounds__(128)
void scan_kernel(const ushort_t* __restrict__ q, const ushort_t* __restrict__ k,
                 const ushort_t* __restrict__ v, const float* __restrict__ beta,
                 const float* __restrict__ g, ushort_t* __restrict__ o)
{
    const int blk = blockIdx.x;
    const int dv0 = (blk & 15) * 16;
    const int h = (blk >> 4) & 3;
    const int b = blk >> 6;
    const int tid = threadIdx.x;
    const int kk = tid & 7;
    const int dvl = tid >> 3;

    __shared__ __align__(16) float sQ[2][288];
    __shared__ __align__(16) float sK[2][2][288];
    __shared__ __align__(16) float sV[2][2][16];

    float S[32];
#pragma unroll
    for (int j = 0; j < 32; j++) S[j] = 0.f;

    const size_t bT = (size_t)b * T_;

    auto stage = [&](int t, int bufi) {
        const size_t bt = bT + t;
        const int i4 = tid & 63;
        const int ki = tid >> 6;
        const float4 kf = cvt4(reinterpret_cast<const short4v*>(k + ((bt * 2 + ki) * 4 + h) * 256)[i4]);
        *reinterpret_cast<float4*>(&sK[bufi][ki][(i4 >> 3) * 36 + (i4 & 7) * 4]) = kf;
        if (tid < 64) {
            const float4 qf = cvt4(reinterpret_cast<const short4v*>(q + (bt * 4 + h) * 256)[tid]);
            *reinterpret_cast<float4*>(&sQ[bufi][(tid >> 3) * 36 + (tid & 7) * 4]) = qf;
        }
        if (tid < 8) {
            const int vi = tid >> 2, j4 = tid & 3;
            const float4 vf = cvt4(*reinterpret_cast<const short4v*>(v + ((bt * 2 + vi) * 4 + h) * 256 + dv0 + j4 * 4));
            *reinterpret_cast<float4*>(&sV[bufi][vi][j4 * 4]) = vf;
        }
    };

    stage(0, 0);
    __syncthreads();
    int buf = 0;
    for (int t = 0; t < T_; ++t) {
        if (t + 1 < T_) stage(t + 1, buf ^ 1);
        const float decay = __expf(g[(bT + t) * 4 + h]);
#pragma unroll
        for (int j = 0; j < 32; j++) S[j] *= decay;
#pragma unroll
        for (int i = 0; i < 2; i++) {
            const float bt_ = beta[(bT + t) * 8 + i * 4 + h];
            float kv[32];
            const float* kp = &sK[buf][i][kk * 36];
#pragma unroll
            for (int j4 = 0; j4 < 8; j4++) {
                const float4 kf = *reinterpret_cast<const float4*>(kp + j4 * 4);
                kv[j4 * 4 + 0] = kf.x; kv[j4 * 4 + 1] = kf.y;
                kv[j4 * 4 + 2] = kf.z; kv[j4 * 4 + 3] = kf.w;
            }
            float pred = 0.f;
#pragma unroll
            for (int j = 0; j < 32; j++) pred += S[j] * kv[j];
            pred += __shfl_xor(pred, 1);
            pred += __shfl_xor(pred, 2);
            pred += __shfl_xor(pred, 4);
            const float u = (sV[buf][i][dvl] - pred) * bt_;
#pragma unroll
            for (int j = 0; j < 32; j++) S[j] += kv[j] * u;
        }
        float op = 0.f;
        const float* qp = &sQ[buf][kk * 36];
#pragma unroll
        for (int j4 = 0; j4 < 8; j4++) {
            const float4 qf = *reinterpret_cast<const float4*>(qp + j4 * 4);
            op += S[j4 * 4 + 0] * qf.x + S[j4 * 4 + 1] * qf.y
                + S[j4 * 4 + 2] * qf.z + S[j4 * 4 + 3] * qf.w;
        }
        op += __shfl_xor(op, 1);
        op += __shfl_xor(op, 2);
        op += __shfl_xor(op, 4);
        if (kk == 0) o[((bT + t) * 4 + h) * 256 + dv0 + dvl] = f2bf(op * 0.0625f);
        __syncthreads();
        buf ^= 1;
    }
}

// silu(g)*u on bf16, in-place into g buffer (4 elems per thread)
__global__ __launch_bounds__(256)
void silu_mul_kernel(ushort_t* __restrict__ gb, const ushort_t* __restrict__ ub)
{
    const size_t i = (size_t)blockIdx.x * 256 + threadIdx.x;
    const float4 gv = cvt4(reinterpret_cast<short4v*>(gb)[i]);
    const float4 uv = cvt4(reinterpret_cast<const short4v*>(ub)[i]);
    float4 r;
    r.x = siluf_(gv.x) * uv.x; r.y = siluf_(gv.y) * uv.y;
    r.z = siluf_(gv.z) * uv.z; r.w = siluf_(gv.w) * uv.w;
    reinterpret_cast<short4v*>(gb)[i] = pack4(r);
}

// copy out[:, T-1, :] to tail of d_out
__global__ __launch_bounds__(256)
void tail_kernel(float* __restrict__ out)
{
    const int i = blockIdx.x * 256 + threadIdx.x;
    const int b = i >> 10, d = i & 1023;
    out[(size_t)B_ * T_ * D_ + i] = out[((size_t)b * T_ + (T_ - 1)) * D_ + d];
}

// ---------------------------------------------------------------------------
extern "C" void kernel_launch(void* const* d_in, const int* in_sizes, int n_in,
                              void* d_out, int out_size, void* d_ws, size_t ws_size,
                              hipStream_t stream)
{
    const float* x    = (const float*)d_in[0];
    const float* prev = (const float*)d_in[1];
    const float* spw  = (const float*)d_in[2];
    const float* sgw  = (const float*)d_in[3];
    const float* sgb  = (const float*)d_in[4];
    const float* anw  = (const float*)d_in[5];
    const float* qw   = (const float*)d_in[6];
    const float* kw   = (const float*)d_in[7];
    const float* vw   = (const float*)d_in[8];
    const float* bw   = (const float*)d_in[9];
    const float* aw   = (const float*)d_in[10];
    const float* Alog = (const float*)d_in[11];
    const float* dtb  = (const float*)d_in[12];
    const float* qcw  = (const float*)d_in[13];
    const float* kcw  = (const float*)d_in[14];
    const float* vcw  = (const float*)d_in[15];
    const float* onw  = (const float*)d_in[16];
    const float* ow   = (const float*)d_in[17];
    const float* mnw  = (const float*)d_in[18];
    const float* gw   = (const float*)d_in[19];
    const float* uw   = (const float*)d_in[20];
    const float* dw   = (const float*)d_in[21];
    float* out = (float*)d_out;

    const size_t NX = (size_t)B_ * T_ * D_;   // 16,777,216
    const int M = B_ * T_;                    // 16384
    const size_t MI = (size_t)M * I_;         // 46,137,344

    // ---- workspace layout (shorts), peak ~242 MB ----
    ushort_t* wsb = (ushort_t*)d_ws;
    size_t off = 0;
    ushort_t* wsc = wsb + off; off += 2883584;   // weight scratch (max I_*D_)
    ushort_t* hb  = wsb + off; off += NX;        // hb / onb / h2b
    ushort_t* raw = wsb + off; off += NX;        // pre-conv chunk; later ob
    ushort_t* qb  = wsb + off; off += NX;
    ushort_t* kb  = wsb + off; off += 2 * NX;    // also hosts xb early
    ushort_t* vb  = wsb + off; off += 2 * NX;
    float*    es   = (float*)(wsb + off);
    float*    esg  = es + (size_t)B_ * D_;
    float*    beta = esg + (size_t)B_ * D_;
    float*    gbuf = beta + (size_t)M * 8;
    // overlays
    ushort_t* xb  = kb;        // bf16(x) for gate GEMM (dead before conv fills kb)
    ushort_t* ob  = raw;       // scan output (raw dead after convs)
    ushort_t* mgb = raw;       // MLP: MI shorts over raw+qb+kb (dead post-scan)
    ushort_t* mub = raw + MI;  // MI shorts, ends within vb
    float*    xf  = out;       // f32 residual stream lives in d_out

    // ---- state fusion ----
    tobf16_kernel<<<(int)(NX / 1024), 256, 0, stream>>>(x, xb);
    tobf16_kernel<<<2048, 256, 0, stream>>>(sgw, wsc);
    es_kernel<<<2048, 256, 0, stream>>>(prev, spw, es);
    esg_kernel<<<2048, 256, 0, stream>>>(es, sgw, sgb, esg);
    gemm_bf16<2><<<dim3(8, 128), 256, 0, stream>>>(
        xb, D_, wsc, 2 * D_, xf, nullptr, M, D_, D_, x, es, esg);

    // ---- attention sub-block ----
    rmsnorm_bf16_kernel<<<M, 256, 0, stream>>>(xf, anw, hb);
    proj_ba_kernel<<<M, 256, 0, stream>>>(hb, bw, aw, Alog, dtb, beta, gbuf);

    // q: one N=1024 chunk
    tobf16_kernel<<<1024, 256, 0, stream>>>(qw, wsc);
    gemm_bf16<0><<<dim3(8, 128), 256, 0, stream>>>(
        hb, D_, wsc, D_, nullptr, raw, M, 1024, D_, nullptr, nullptr, nullptr);
    conv_silu_kernel<<<16384, 256, 0, stream>>>(raw, qcw, qb, 256, 256, 0, 0);

    // k: two N=1024 chunks
    tobf16_kernel<<<2048, 256, 0, stream>>>(kw, wsc);
    for (int j = 0; j < 2; j++) {
        gemm_bf16<0><<<dim3(8, 128), 256, 0, stream>>>(
            hb, D_, wsc + (size_t)j * 1024 * D_, D_, nullptr, raw, M, 1024, D_,
            nullptr, nullptr, nullptr);
        conv_silu_kernel<<<16384, 256, 0, stream>>>(raw, kcw, kb, 256, 512, j * 256, j * 1024);
    }

    // v: two N=1024 chunks
    tobf16_kernel<<<2048, 256, 0, stream>>>(vw, wsc);
    for (int j = 0; j < 2; j++) {
        gemm_bf16<0><<<dim3(8, 128), 256, 0, stream>>>(
            hb, D_, wsc + (size_t)j * 1024 * D_, D_, nullptr, raw, M, 1024, D_,
            nullptr, nullptr, nullptr);
        conv_silu_kernel<<<16384, 256, 0, stream>>>(raw, vcw, vb, 256, 512, j * 256, j * 1024);
    }

    l2n_kernel<<<16384, 256, 0, stream>>>(qb);
    l2n_kernel<<<32768, 256, 0, stream>>>(kb);

    scan_kernel<<<512, 128, 0, stream>>>(qb, kb, vb, beta, gbuf, ob);

    onorm_bf16_kernel<<<16384, 256, 0, stream>>>(ob, onw, hb);
    tobf16_kernel<<<1024, 256, 0, stream>>>(ow, wsc);
    gemm_bf16<1><<<dim3(8, 128), 256, 0, stream>>>(
        hb, D_, wsc, D_, out, nullptr, M, 1024, D_, xf, nullptr, nullptr);

    // ---- MLP sub-block ----
    rmsnorm_bf16_kernel<<<M, 256, 0, stream>>>(out, mnw, hb);
    tobf16_kernel<<<2816, 256, 0, stream>>>(gw, wsc);
    gemm_bf16<0><<<dim3(22, 128), 256, 0, stream>>>(
        hb, D_, wsc, D_, nullptr, mgb, M, I_, D_, nullptr, nullptr, nullptr);
    tobf16_kernel<<<2816, 256, 0, stream>>>(uw, wsc);
    gemm_bf16<0><<<dim3(22, 128), 256, 0, stream>>>(
        hb, D_, wsc, D_, nullptr, mub, M, I_, D_, nullptr, nullptr, nullptr);
    silu_mul_kernel<<<(int)((MI / 4) / 256), 256, 0, stream>>>(mgb, mub);
    tobf16_kernel<<<2816, 256, 0, stream>>>(dw, wsc);
    gemm_bf16<1><<<dim3(8, 128), 256, 0, stream>>>(
        mgb, I_, wsc, I_, out, nullptr, M, 1024, I_, out, nullptr, nullptr);

    tail_kernel<<<32, 256, 0, stream>>>(out);
}

// Round 6
// 3351.496 us; speedup vs baseline: 1.5315x; 1.5315x over previous
//
#include <hip/hip_runtime.h>
#include <stdint.h>

#define B_ 8
#define T_ 2048
#define D_ 1024
#define H_ 4
#define DK_ 256
#define DV_ 256
#define NH_ 2
#define I_ 2816
#define EPS_ 1e-6f

typedef __attribute__((ext_vector_type(4))) short short4v;
typedef __attribute__((ext_vector_type(8))) short bf16x8;
typedef __attribute__((ext_vector_type(4))) float f32x4;
typedef unsigned short ushort_t;

__device__ __forceinline__ unsigned short f2bf(float f) {
    union { float f; unsigned int u; } c; c.f = f;
    unsigned int r = c.u + 0x7FFFu + ((c.u >> 16) & 1u);
    return (unsigned short)(r >> 16);
}
__device__ __forceinline__ float bf2f(unsigned short s) {
    union { unsigned int u; float f; } c; c.u = ((unsigned int)s) << 16;
    return c.f;
}
__device__ __forceinline__ short4v pack4(float4 v) {
    short4v r;
    r.x = (short)f2bf(v.x); r.y = (short)f2bf(v.y);
    r.z = (short)f2bf(v.z); r.w = (short)f2bf(v.w);
    return r;
}
__device__ __forceinline__ float4 cvt4(short4v s) {
    float4 r;
    r.x = bf2f((unsigned short)s.x); r.y = bf2f((unsigned short)s.y);
    r.z = bf2f((unsigned short)s.z); r.w = bf2f((unsigned short)s.w);
    return r;
}
__device__ __forceinline__ float sigmoidf_(float x) { return 1.f / (1.f + __expf(-x)); }
__device__ __forceinline__ float siluf_(float x)    { return x / (1.f + __expf(-x)); }

// async global->LDS, 16 bytes per lane; LDS dest = wave-uniform base + lane*16
__device__ __forceinline__ void gll16(const ushort_t* g, ushort_t* l) {
    __builtin_amdgcn_global_load_lds(
        (const __attribute__((address_space(1))) uint32_t*)g,
        (__attribute__((address_space(3))) uint32_t*)l, 16, 0, 0);
}

// ---------------------------------------------------------------------------
// bf16 MFMA GEMM (m97 structure): acc = A[M,K] @ W[N,K]^T
// EPI 0: Cb = bf16(acc)
// EPI 1: Cf = acc + e0f[idx]   (f32 residual out; e0f may alias Cf, same idx)
// EPI 2: Cf = gate-blend f32: g = sigmoid(acc + e2f[b,col]);
//             Cf = g*e0f[idx] + (1-g)*e1f[b,col]
// ---------------------------------------------------------------------------
template<int EPI>
__global__ __launch_bounds__(256)
void gemm_bf16(const ushort_t* __restrict__ A, int lda,
               const ushort_t* __restrict__ W, int ldw,
               float* __restrict__ Cf, ushort_t* __restrict__ Cb,
               int M, int N, int K,
               const float* __restrict__ e0f,
               const float* __restrict__ e1f,
               const float* __restrict__ e2f)
{
    __shared__ ushort_t As[128 * 32];
    __shared__ ushort_t Bs[128 * 32];
    const int tid = threadIdx.x;
    const int m0 = blockIdx.y * 128;
    const int n0 = blockIdx.x * 128;
    const int lane = tid & 63;
    const int wv = tid >> 6;
    const int wm = (wv >> 1) * 64, wn = (wv & 1) * 64;
    const int lr = lane & 15, lk = lane >> 4;
    const int srow = lane >> 2;
    const int scol = (lane & 3) * 8;

    f32x4 acc[4][4];
#pragma unroll
    for (int i = 0; i < 4; i++)
#pragma unroll
        for (int j = 0; j < 4; j++) acc[i][j] = (f32x4){0.f, 0.f, 0.f, 0.f};

    const ushort_t* Ab = A + (size_t)m0 * lda;
    const ushort_t* Wb = W + (size_t)n0 * ldw;

    for (int k0 = 0; k0 < K; k0 += 32) {
#pragma unroll
        for (int i = 0; i < 2; i++) {
            const int c = wv * 2 + i;
            const int row = c * 16 + srow;
            gll16(Ab + (size_t)row * lda + k0 + scol, &As[c * 512]);
            gll16(Wb + (size_t)row * ldw + k0 + scol, &Bs[c * 512]);
        }
        __syncthreads();
        bf16x8 af[4], bq[4];
#pragma unroll
        for (int mi = 0; mi < 4; mi++)
            af[mi] = *reinterpret_cast<const bf16x8*>(&As[(wm + mi * 16 + lr) * 32 + lk * 8]);
#pragma unroll
        for (int ni = 0; ni < 4; ni++)
            bq[ni] = *reinterpret_cast<const bf16x8*>(&Bs[(wn + ni * 16 + lr) * 32 + lk * 8]);
#pragma unroll
        for (int mi = 0; mi < 4; mi++)
#pragma unroll
            for (int ni = 0; ni < 4; ni++)
                acc[mi][ni] = __builtin_amdgcn_mfma_f32_16x16x32_bf16(af[mi], bq[ni], acc[mi][ni], 0, 0, 0);
        __syncthreads();
    }

#pragma unroll
    for (int mi = 0; mi < 4; mi++) {
#pragma unroll
        for (int ni = 0; ni < 4; ni++) {
            const int col = n0 + wn + ni * 16 + lr;
#pragma unroll
            for (int rr = 0; rr < 4; rr++) {
                const int row = m0 + wm + mi * 16 + lk * 4 + rr;
                const size_t idx = (size_t)row * N + col;
                const float val = acc[mi][ni][rr];
                if (EPI == 0) {
                    Cb[idx] = f2bf(val);
                } else if (EPI == 1) {
                    Cf[idx] = val + e0f[idx];
                } else {
                    const int b = row >> 11;
                    const float gate = sigmoidf_(val + e2f[b * D_ + col]);
                    Cf[idx] = gate * e0f[idx] + (1.f - gate) * e1f[b * D_ + col];
                }
            }
        }
    }
}

// fp32 -> bf16 (float4 per thread)
__global__ __launch_bounds__(256)
void tobf16_kernel(const float* __restrict__ in, ushort_t* __restrict__ out)
{
    const size_t i = (size_t)blockIdx.x * 256 + threadIdx.x;
    const float4 v = reinterpret_cast<const float4*>(in)[i];
    *reinterpret_cast<short4v*>(&out[i * 4]) = pack4(v);
}

// es[b,j] = prev[b,:] . state_proj_w[j,:]  (one wave per output)
__global__ __launch_bounds__(256)
void es_kernel(const float* __restrict__ prev, const float* __restrict__ spw,
               float* __restrict__ es)
{
    const int out = blockIdx.x * 4 + (threadIdx.x >> 6);
    const int lane = threadIdx.x & 63;
    const int b = out >> 10, j = out & 1023;
    const float4* pr = reinterpret_cast<const float4*>(prev + (size_t)b * D_);
    const float4* wr = reinterpret_cast<const float4*>(spw + (size_t)j * D_);
    float acc = 0.f;
#pragma unroll
    for (int p = 0; p < 4; p++) {
        float4 a = pr[lane + 64 * p], w = wr[lane + 64 * p];
        acc += a.x * w.x + a.y * w.y + a.z * w.z + a.w * w.w;
    }
#pragma unroll
    for (int m = 1; m < 64; m <<= 1) acc += __shfl_xor(acc, m);
    if (lane == 0) es[out] = acc;
}

// esg[b,d] = es[b,:] . state_gate_w[d, D:2D] + state_gate_b[d]
__global__ __launch_bounds__(256)
void esg_kernel(const float* __restrict__ es, const float* __restrict__ sgw,
                const float* __restrict__ sgb, float* __restrict__ esg)
{
    const int out = blockIdx.x * 4 + (threadIdx.x >> 6);
    const int lane = threadIdx.x & 63;
    const int b = out >> 10, d = out & 1023;
    const float4* er = reinterpret_cast<const float4*>(es + (size_t)b * D_);
    const float4* wr = reinterpret_cast<const float4*>(sgw + (size_t)d * (2 * D_) + D_);
    float acc = 0.f;
#pragma unroll
    for (int p = 0; p < 4; p++) {
        float4 a = er[lane + 64 * p], w = wr[lane + 64 * p];
        acc += a.x * w.x + a.y * w.y + a.z * w.z + a.w * w.w;
    }
#pragma unroll
    for (int m = 1; m < 64; m <<= 1) acc += __shfl_xor(acc, m);
    if (lane == 0) esg[out] = acc + sgb[d];
}

// RMSNorm rows of 1024, f32 in -> bf16 out
__global__ __launch_bounds__(256)
void rmsnorm_bf16_kernel(const float* __restrict__ x, const float* __restrict__ w,
                         ushort_t* __restrict__ y)
{
    const int row = blockIdx.x;
    const int tid = threadIdx.x;
    const float4 v = reinterpret_cast<const float4*>(x + (size_t)row * D_)[tid];
    float ss = v.x * v.x + v.y * v.y + v.z * v.z + v.w * v.w;
#pragma unroll
    for (int m = 1; m < 64; m <<= 1) ss += __shfl_xor(ss, m);
    __shared__ float red[4];
    if ((tid & 63) == 0) red[tid >> 6] = ss;
    __syncthreads();
    ss = red[0] + red[1] + red[2] + red[3];
    const float rs = rsqrtf(ss * (1.f / 1024.f) + EPS_);
    const float4 wv = reinterpret_cast<const float4*>(w)[tid];
    float4 r;
    r.x = v.x * rs * wv.x; r.y = v.y * rs * wv.y;
    r.z = v.z * rs * wv.z; r.w = v.w * rs * wv.w;
    *reinterpret_cast<short4v*>(&y[(size_t)row * D_ + tid * 4]) = pack4(r);
}

// per-head RMSNorm rows of 256, bf16 in -> bf16 out (one wave per row)
__global__ __launch_bounds__(256)
void onorm_bf16_kernel(const ushort_t* __restrict__ x, const float* __restrict__ w,
                       ushort_t* __restrict__ y)
{
    const int row = blockIdx.x * 4 + (threadIdx.x >> 6);
    const int lane = threadIdx.x & 63;
    const float4 v = cvt4(reinterpret_cast<const short4v*>(x + (size_t)row * 256)[lane]);
    float ss = v.x * v.x + v.y * v.y + v.z * v.z + v.w * v.w;
#pragma unroll
    for (int m = 1; m < 64; m <<= 1) ss += __shfl_xor(ss, m);
    const float rs = rsqrtf(ss * (1.f / 256.f) + EPS_);
    const float4 wv = reinterpret_cast<const float4*>(w)[lane];
    float4 r;
    r.x = v.x * rs * wv.x; r.y = v.y * rs * wv.y;
    r.z = v.z * rs * wv.z; r.w = v.w * rs * wv.w;
    *reinterpret_cast<short4v*>(&y[(size_t)row * 256 + lane * 4]) = pack4(r);
}

// l2 normalize rows of 256 in-place, bf16 (one wave per row)
__global__ __launch_bounds__(256)
void l2n_kernel(ushort_t* __restrict__ x)
{
    const int row = blockIdx.x * 4 + (threadIdx.x >> 6);
    const int lane = threadIdx.x & 63;
    short4v* xr = reinterpret_cast<short4v*>(x + (size_t)row * 256);
    float4 v = cvt4(xr[lane]);
    float ss = v.x * v.x + v.y * v.y + v.z * v.z + v.w * v.w;
#pragma unroll
    for (int m = 1; m < 64; m <<= 1) ss += __shfl_xor(ss, m);
    const float rs = rsqrtf(ss + EPS_);
    v.x *= rs; v.y *= rs; v.z *= rs; v.w *= rs;
    xr[lane] = pack4(v);
}

// causal depthwise conv (K=4) + SiLU, bf16 in/out
__global__ __launch_bounds__(256)
void conv_silu_kernel(const ushort_t* __restrict__ x, const float* __restrict__ w,
                      ushort_t* __restrict__ y, int inC4, int outC4, int outOff4,
                      int chOff4)
{
    const size_t gid = (size_t)blockIdx.x * 256 + threadIdx.x;
    const int c4 = (int)(gid % inC4);
    const size_t bt = gid / inC4;
    const int t = (int)(bt & (T_ - 1));
    const short4v* xr = reinterpret_cast<const short4v*>(x) + bt * inC4 + c4;
    const float4* wr = reinterpret_cast<const float4*>(w) + chOff4 + (size_t)c4 * 4;
    const float4 w0 = wr[0], w1 = wr[1], w2 = wr[2], w3 = wr[3];
    const float4 z = {0.f, 0.f, 0.f, 0.f};
    const float4 x3 = cvt4(xr[0]);
    const float4 x2v = (t >= 1) ? cvt4(xr[-(ptrdiff_t)inC4]) : z;
    const float4 x1v = (t >= 2) ? cvt4(xr[-2 * (ptrdiff_t)inC4]) : z;
    const float4 x0v = (t >= 3) ? cvt4(xr[-3 * (ptrdiff_t)inC4]) : z;
    float4 a;
    a.x = x0v.x * w0.x + x1v.x * w0.y + x2v.x * w0.z + x3.x * w0.w;
    a.y = x0v.y * w1.x + x1v.y * w1.y + x2v.y * w1.z + x3.y * w1.w;
    a.z = x0v.z * w2.x + x1v.z * w2.y + x2v.z * w2.z + x3.z * w2.w;
    a.w = x0v.w * w3.x + x1v.w * w3.y + x2v.w * w3.z + x3.w * w3.w;
    float4 r;
    r.x = siluf_(a.x); r.y = siluf_(a.y); r.z = siluf_(a.z); r.w = siluf_(a.w);
    reinterpret_cast<short4v*>(y)[bt * outC4 + outOff4 + c4] = pack4(r);
}

// beta/g projections (N=12) from bf16 h
__global__ __launch_bounds__(256)
void proj_ba_kernel(const ushort_t* __restrict__ hb, const float* __restrict__ bw,
                    const float* __restrict__ aw, const float* __restrict__ Alog,
                    const float* __restrict__ dtb,
                    float* __restrict__ beta, float* __restrict__ g)
{
    const int row = blockIdx.x;
    const int wv = threadIdx.x >> 6, lane = threadIdx.x & 63;
    const ushort_t* hr = hb + (size_t)row * D_;
#pragma unroll
    for (int s = 0; s < 3; s++) {
        const int o = wv * 3 + s;
        const float* wrow = (o < 8) ? (bw + (size_t)o * D_) : (aw + (size_t)(o - 8) * D_);
        const float4* wr4 = reinterpret_cast<const float4*>(wrow);
        float acc = 0.f;
#pragma unroll
        for (int p = 0; p < 2; p++) {
            const int gg = lane + 64 * p;
            const bf16x8 hv = *reinterpret_cast<const bf16x8*>(&hr[gg * 8]);
            const float4 wa = wr4[gg * 2], wb2 = wr4[gg * 2 + 1];
            acc += bf2f((unsigned short)hv[0]) * wa.x + bf2f((unsigned short)hv[1]) * wa.y
                 + bf2f((unsigned short)hv[2]) * wa.z + bf2f((unsigned short)hv[3]) * wa.w
                 + bf2f((unsigned short)hv[4]) * wb2.x + bf2f((unsigned short)hv[5]) * wb2.y
                 + bf2f((unsigned short)hv[6]) * wb2.z + bf2f((unsigned short)hv[7]) * wb2.w;
        }
#pragma unroll
        for (int m = 1; m < 64; m <<= 1) acc += __shfl_xor(acc, m);
        if (lane == 0) {
            if (o < 8) {
                beta[(size_t)row * 8 + o] = 2.f * sigmoidf_(acc);
            } else {
                const int hh = o - 8;
                const float xg = acc + dtb[hh];
                const float sp = (xg > 20.f) ? xg : log1pf(expf(xg));
                g[(size_t)row * 4 + hh] = -expf(Alog[hh]) * sp;
            }
        }
    }
}

// ---------------------------------------------------------------------------
// sequential gated delta-product scan, v2: group-staged (GT=8 tokens/group),
// T14 async split (load->regs early, LDS-write late), 1 barrier/group.
// grid = 512 blocks (XCD-swizzled so the 16 dv-chunks of one (b,h) share an
// XCD's L2), 256 threads: kk = tid&15 (16 k-groups of 16), dvl = tid>>4.
// Thread owns S[kk*16+j][dv0+dvl], j=0..15 (f32).
// LDS rows: 16 groups * stride 20 floats (16B-aligned b128, worst 2-way bank).
// ---------------------------------------------------------------------------
#define GT 8
__global__ __launch_bounds__(256)
void scan_kernel(const ushort_t* __restrict__ q, const ushort_t* __restrict__ k,
                 const ushort_t* __restrict__ v, const float* __restrict__ beta,
                 const float* __restrict__ g, ushort_t* __restrict__ o)
{
    // XCD-bijective remap: 16 dv-chunks of (b,h) -> same (d mod 8)
    const int d = blockIdx.x;
    const int m = d >> 3;
    const int bh = (d & 7) * 4 + (m >> 4);
    const int dvc = m & 15;
    const int b = bh >> 2, h = bh & 3;
    const int dv0 = dvc * 16;
    const int tid = threadIdx.x;
    const int kk = tid & 15;
    const int dvl = tid >> 4;

    __shared__ __align__(16) float sQ[2][GT][320];
    __shared__ __align__(16) float sK[2][GT][2][320];
    __shared__ __align__(16) float sV[2][GT][2][16];
    __shared__ float sB[2][GT][2];
    __shared__ float sG[2][GT];

    float S[16];
#pragma unroll
    for (int j = 0; j < 16; j++) S[j] = 0.f;

    const size_t bT = (size_t)b * T_;

    // staging registers
    short4v rq0, rq1, rk00, rk01, rk10, rk11, rv0, rv1;
    float rb = 0.f, rg = 0.f;

    auto stage_load = [&](int grp) {
        const size_t t0 = bT + (size_t)grp * GT;
        {   // q: 8 tok x 256 -> thread (tid>>5, (tid&31)*8)
            const int tq = tid >> 5, e = (tid & 31) * 8;
            const ushort_t* qp = q + ((t0 + tq) * 4 + h) * 256 + e;
            rq0 = *reinterpret_cast<const short4v*>(qp);
            rq1 = *reinterpret_cast<const short4v*>(qp + 4);
        }
        {   // k pass 0: idx = tid*8
            const int idx = tid * 8;
            const int tk = idx >> 9, ii = (idx >> 8) & 1, e = idx & 255;
            const ushort_t* kp = k + (((t0 + tk) * 2 + ii) * 4 + h) * 256 + e;
            rk00 = *reinterpret_cast<const short4v*>(kp);
            rk01 = *reinterpret_cast<const short4v*>(kp + 4);
        }
        {   // k pass 1: idx = 2048 + tid*8
            const int idx = 2048 + tid * 8;
            const int tk = idx >> 9, ii = (idx >> 8) & 1, e = idx & 255;
            const ushort_t* kp = k + (((t0 + tk) * 2 + ii) * 4 + h) * 256 + e;
            rk10 = *reinterpret_cast<const short4v*>(kp);
            rk11 = *reinterpret_cast<const short4v*>(kp + 4);
        }
        if (tid < 32) {   // v slice: 8 tok x 2 i x 16
            const int tv = tid >> 2, ii = (tid >> 1) & 1, e8 = (tid & 1) * 8;
            const ushort_t* vp = v + (((t0 + tv) * 2 + ii) * 4 + h) * 256 + dv0 + e8;
            rv0 = *reinterpret_cast<const short4v*>(vp);
            rv1 = *reinterpret_cast<const short4v*>(vp + 4);
        }
        if (tid < 16) rb = beta[(t0 + (tid >> 1)) * 8 + (tid & 1) * 4 + h];
        else if (tid < 24) rg = g[(t0 + (tid - 16)) * 4 + h];
    };

    auto stage_write = [&](int bufi) {
        {
            const int tq = tid >> 5, e = (tid & 31) * 8;
            float* dst = &sQ[bufi][tq][(e >> 4) * 20 + (e & 15)];
            *reinterpret_cast<float4*>(dst) = cvt4(rq0);
            *reinterpret_cast<float4*>(dst + 4) = cvt4(rq1);
        }
        {
            const int idx = tid * 8;
            const int tk = idx >> 9, ii = (idx >> 8) & 1, e = idx & 255;
            float* dst = &sK[bufi][tk][ii][(e >> 4) * 20 + (e & 15)];
            *reinterpret_cast<float4*>(dst) = cvt4(rk00);
            *reinterpret_cast<float4*>(dst + 4) = cvt4(rk01);
        }
        {
            const int idx = 2048 + tid * 8;
            const int tk = idx >> 9, ii = (idx >> 8) & 1, e = idx & 255;
            float* dst = &sK[bufi][tk][ii][(e >> 4) * 20 + (e & 15)];
            *reinterpret_cast<float4*>(dst) = cvt4(rk10);
            *reinterpret_cast<float4*>(dst + 4) = cvt4(rk11);
        }
        if (tid < 32) {
            const int tv = tid >> 2, ii = (tid >> 1) & 1, e8 = (tid & 1) * 8;
            float* dst = &sV[bufi][tv][ii][e8];
            *reinterpret_cast<float4*>(dst) = cvt4(rv0);
            *reinterpret_cast<float4*>(dst + 4) = cvt4(rv1);
        }
        if (tid < 16) sB[bufi][tid >> 1][tid & 1] = rb;
        else if (tid < 24) sG[bufi][tid - 16] = rg;
    };

    stage_load(0);
    stage_write(0);
    __syncthreads();
    int buf = 0;
    const int NG = T_ / GT;
    for (int grp = 0; grp < NG; ++grp) {
        if (grp + 1 < NG) stage_load(grp + 1);   // HBM latency hides under 8-token compute
#pragma unroll
        for (int tt = 0; tt < GT; ++tt) {
            const float decay = __expf(sG[buf][tt]);
#pragma unroll
            for (int j = 0; j < 16; j++) S[j] *= decay;
#pragma unroll
            for (int i = 0; i < 2; i++) {
                const float* kp = &sK[buf][tt][i][kk * 20];
                const float4 k0 = *reinterpret_cast<const float4*>(kp);
                const float4 k1 = *reinterpret_cast<const float4*>(kp + 4);
                const float4 k2 = *reinterpret_cast<const float4*>(kp + 8);
                const float4 k3 = *reinterpret_cast<const float4*>(kp + 12);
                float kv[16] = {k0.x, k0.y, k0.z, k0.w, k1.x, k1.y, k1.z, k1.w,
                                k2.x, k2.y, k2.z, k2.w, k3.x, k3.y, k3.z, k3.w};
                float p0 = 0.f, p1 = 0.f, p2 = 0.f, p3 = 0.f;
#pragma unroll
                for (int j = 0; j < 4; j++) {
                    p0 += S[j] * kv[j];
                    p1 += S[4 + j] * kv[4 + j];
                    p2 += S[8 + j] * kv[8 + j];
                    p3 += S[12 + j] * kv[12 + j];
                }
                float pred = (p0 + p1) + (p2 + p3);
                pred += __shfl_xor(pred, 1);
                pred += __shfl_xor(pred, 2);
                pred += __shfl_xor(pred, 4);
                pred += __shfl_xor(pred, 8);
                const float u = (sV[buf][tt][i][dvl] - pred) * sB[buf][tt][i];
#pragma unroll
                for (int j = 0; j < 16; j++) S[j] += kv[j] * u;
            }
            const float* qp = &sQ[buf][tt][kk * 20];
            const float4 q0 = *reinterpret_cast<const float4*>(qp);
            const float4 q1 = *reinterpret_cast<const float4*>(qp + 4);
            const float4 q2 = *reinterpret_cast<const float4*>(qp + 8);
            const float4 q3 = *reinterpret_cast<const float4*>(qp + 12);
            float o0 = S[0]*q0.x + S[1]*q0.y + S[2]*q0.z + S[3]*q0.w;
            float o1 = S[4]*q1.x + S[5]*q1.y + S[6]*q1.z + S[7]*q1.w;
            float o2 = S[8]*q2.x + S[9]*q2.y + S[10]*q2.z + S[11]*q2.w;
            float o3 = S[12]*q3.x + S[13]*q3.y + S[14]*q3.z + S[15]*q3.w;
            float op = (o0 + o1) + (o2 + o3);
            op += __shfl_xor(op, 1);
            op += __shfl_xor(op, 2);
            op += __shfl_xor(op, 4);
            op += __shfl_xor(op, 8);
            if (kk == 0)
                o[((bT + (size_t)grp * GT + tt) * 4 + h) * 256 + dv0 + dvl] = f2bf(op * 0.0625f);
        }
        if (grp + 1 < NG) stage_write(buf ^ 1);  // after compute: loads have landed
        __syncthreads();
        buf ^= 1;
    }
}

// silu(g)*u on bf16, in-place into g buffer (4 elems per thread)
__global__ __launch_bounds__(256)
void silu_mul_kernel(ushort_t* __restrict__ gb, const ushort_t* __restrict__ ub)
{
    const size_t i = (size_t)blockIdx.x * 256 + threadIdx.x;
    const float4 gv = cvt4(reinterpret_cast<short4v*>(gb)[i]);
    const float4 uv = cvt4(reinterpret_cast<const short4v*>(ub)[i]);
    float4 r;
    r.x = siluf_(gv.x) * uv.x; r.y = siluf_(gv.y) * uv.y;
    r.z = siluf_(gv.z) * uv.z; r.w = siluf_(gv.w) * uv.w;
    reinterpret_cast<short4v*>(gb)[i] = pack4(r);
}

// copy out[:, T-1, :] to tail of d_out
__global__ __launch_bounds__(256)
void tail_kernel(float* __restrict__ out)
{
    const int i = blockIdx.x * 256 + threadIdx.x;
    const int b = i >> 10, d = i & 1023;
    out[(size_t)B_ * T_ * D_ + i] = out[((size_t)b * T_ + (T_ - 1)) * D_ + d];
}

// ---------------------------------------------------------------------------
extern "C" void kernel_launch(void* const* d_in, const int* in_sizes, int n_in,
                              void* d_out, int out_size, void* d_ws, size_t ws_size,
                              hipStream_t stream)
{
    const float* x    = (const float*)d_in[0];
    const float* prev = (const float*)d_in[1];
    const float* spw  = (const float*)d_in[2];
    const float* sgw  = (const float*)d_in[3];
    const float* sgb  = (const float*)d_in[4];
    const float* anw  = (const float*)d_in[5];
    const float* qw   = (const float*)d_in[6];
    const float* kw   = (const float*)d_in[7];
    const float* vw   = (const float*)d_in[8];
    const float* bw   = (const float*)d_in[9];
    const float* aw   = (const float*)d_in[10];
    const float* Alog = (const float*)d_in[11];
    const float* dtb  = (const float*)d_in[12];
    const float* qcw  = (const float*)d_in[13];
    const float* kcw  = (const float*)d_in[14];
    const float* vcw  = (const float*)d_in[15];
    const float* onw  = (const float*)d_in[16];
    const float* ow   = (const float*)d_in[17];
    const float* mnw  = (const float*)d_in[18];
    const float* gw   = (const float*)d_in[19];
    const float* uw   = (const float*)d_in[20];
    const float* dw   = (const float*)d_in[21];
    float* out = (float*)d_out;

    const size_t NX = (size_t)B_ * T_ * D_;   // 16,777,216
    const int M = B_ * T_;                    // 16384
    const size_t MI = (size_t)M * I_;         // 46,137,344

    // ---- workspace layout (shorts), peak ~242 MB ----
    ushort_t* wsb = (ushort_t*)d_ws;
    size_t off = 0;
    ushort_t* wsc = wsb + off; off += 2883584;   // weight scratch (max I_*D_)
    ushort_t* hb  = wsb + off; off += NX;        // hb / onb / h2b
    ushort_t* raw = wsb + off; off += NX;        // pre-conv chunk; later ob
    ushort_t* qb  = wsb + off; off += NX;
    ushort_t* kb  = wsb + off; off += 2 * NX;    // also hosts xb early
    ushort_t* vb  = wsb + off; off += 2 * NX;
    float*    es   = (float*)(wsb + off);
    float*    esg  = es + (size_t)B_ * D_;
    float*    beta = esg + (size_t)B_ * D_;
    float*    gbuf = beta + (size_t)M * 8;
    // overlays
    ushort_t* xb  = kb;        // bf16(x) for gate GEMM (dead before conv fills kb)
    ushort_t* ob  = raw;       // scan output (raw dead after convs)
    ushort_t* mgb = raw;       // MLP: MI shorts over raw+qb+kb (dead post-scan)
    ushort_t* mub = raw + MI;  // MI shorts, ends within vb
    float*    xf  = out;       // f32 residual stream lives in d_out

    // ---- state fusion ----
    tobf16_kernel<<<(int)(NX / 1024), 256, 0, stream>>>(x, xb);
    tobf16_kernel<<<2048, 256, 0, stream>>>(sgw, wsc);
    es_kernel<<<2048, 256, 0, stream>>>(prev, spw, es);
    esg_kernel<<<2048, 256, 0, stream>>>(es, sgw, sgb, esg);
    gemm_bf16<2><<<dim3(8, 128), 256, 0, stream>>>(
        xb, D_, wsc, 2 * D_, xf, nullptr, M, D_, D_, x, es, esg);

    // ---- attention sub-block ----
    rmsnorm_bf16_kernel<<<M, 256, 0, stream>>>(xf, anw, hb);
    proj_ba_kernel<<<M, 256, 0, stream>>>(hb, bw, aw, Alog, dtb, beta, gbuf);

    // q: one N=1024 chunk
    tobf16_kernel<<<1024, 256, 0, stream>>>(qw, wsc);
    gemm_bf16<0><<<dim3(8, 128), 256, 0, stream>>>(
        hb, D_, wsc, D_, nullptr, raw, M, 1024, D_, nullptr, nullptr, nullptr);
    conv_silu_kernel<<<16384, 256, 0, stream>>>(raw, qcw, qb, 256, 256, 0, 0);

    // k: two N=1024 chunks
    tobf16_kernel<<<2048, 256, 0, stream>>>(kw, wsc);
    for (int j = 0; j < 2; j++) {
        gemm_bf16<0><<<dim3(8, 128), 256, 0, stream>>>(
            hb, D_, wsc + (size_t)j * 1024 * D_, D_, nullptr, raw, M, 1024, D_,
            nullptr, nullptr, nullptr);
        conv_silu_kernel<<<16384, 256, 0, stream>>>(raw, kcw, kb, 256, 512, j * 256, j * 1024);
    }

    // v: two N=1024 chunks
    tobf16_kernel<<<2048, 256, 0, stream>>>(vw, wsc);
    for (int j = 0; j < 2; j++) {
        gemm_bf16<0><<<dim3(8, 128), 256, 0, stream>>>(
            hb, D_, wsc + (size_t)j * 1024 * D_, D_, nullptr, raw, M, 1024, D_,
            nullptr, nullptr, nullptr);
        conv_silu_kernel<<<16384, 256, 0, stream>>>(raw, vcw, vb, 256, 512, j * 256, j * 1024);
    }

    l2n_kernel<<<16384, 256, 0, stream>>>(qb);
    l2n_kernel<<<32768, 256, 0, stream>>>(kb);

    scan_kernel<<<512, 256, 0, stream>>>(qb, kb, vb, beta, gbuf, ob);

    onorm_bf16_kernel<<<16384, 256, 0, stream>>>(ob, onw, hb);
    tobf16_kernel<<<1024, 256, 0, stream>>>(ow, wsc);
    gemm_bf16<1><<<dim3(8, 128), 256, 0, stream>>>(
        hb, D_, wsc, D_, out, nullptr, M, 1024, D_, xf, nullptr, nullptr);

    // ---- MLP sub-block ----
    rmsnorm_bf16_kernel<<<M, 256, 0, stream>>>(out, mnw, hb);
    tobf16_kernel<<<2816, 256, 0, stream>>>(gw, wsc);
    gemm_bf16<0><<<dim3(22, 128), 256, 0, stream>>>(
        hb, D_, wsc, D_, nullptr, mgb, M, I_, D_, nullptr, nullptr, nullptr);
    tobf16_kernel<<<2816, 256, 0, stream>>>(uw, wsc);
    gemm_bf16<0><<<dim3(22, 128), 256, 0, stream>>>(
        hb, D_, wsc, D_, nullptr, mub, M, I_, D_, nullptr, nullptr, nullptr);
    silu_mul_kernel<<<(int)((MI / 4) / 256), 256, 0, stream>>>(mgb, mub);
    tobf16_kernel<<<2816, 256, 0, stream>>>(dw, wsc);
    gemm_bf16<1><<<dim3(8, 128), 256, 0, stream>>>(
        mgb, I_, wsc, I_, out, nullptr, M, 1024, I_, out, nullptr, nullptr);

    tail_kernel<<<32, 256, 0, stream>>>(out);
}

// Round 8
// 2800.123 us; speedup vs baseline: 1.8330x; 1.1969x over previous
//
#include <hip/hip_runtime.h>
#include <stdint.h>

#define B_ 8
#define T_ 2048
#define D_ 1024
#define H_ 4
#define DK_ 256
#define DV_ 256
#define NH_ 2
#define I_ 2816
#define EPS_ 1e-6f

typedef __attribute__((ext_vector_type(4))) short short4v;
typedef __attribute__((ext_vector_type(8))) short bf16x8;
typedef __attribute__((ext_vector_type(4))) float f32x4;
typedef unsigned short ushort_t;

__device__ __forceinline__ unsigned short f2bf(float f) {
    union { float f; unsigned int u; } c; c.f = f;
    unsigned int r = c.u + 0x7FFFu + ((c.u >> 16) & 1u);
    return (unsigned short)(r >> 16);
}
__device__ __forceinline__ float bf2f(unsigned short s) {
    union { unsigned int u; float f; } c; c.u = ((unsigned int)s) << 16;
    return c.f;
}
__device__ __forceinline__ short4v pack4(float4 v) {
    short4v r;
    r.x = (short)f2bf(v.x); r.y = (short)f2bf(v.y);
    r.z = (short)f2bf(v.z); r.w = (short)f2bf(v.w);
    return r;
}
__device__ __forceinline__ float4 cvt4(short4v s) {
    float4 r;
    r.x = bf2f((unsigned short)s.x); r.y = bf2f((unsigned short)s.y);
    r.z = bf2f((unsigned short)s.z); r.w = bf2f((unsigned short)s.w);
    return r;
}
__device__ __forceinline__ float sigmoidf_(float x) { return 1.f / (1.f + __expf(-x)); }
__device__ __forceinline__ float siluf_(float x)    { return x / (1.f + __expf(-x)); }

// VALU cross-lane reduce over aligned 16-lane groups (DPP rows) — no LDS ops,
// so the in-order lgkm queue never serializes surrounding ds_reads.
// dpp_ctrl must be an ICE -> template parameter.
template<int CTRL>
__device__ __forceinline__ float dpp_add_(float x) {
    int y = __builtin_amdgcn_update_dpp(0, __float_as_int(x), CTRL, 0xf, 0xf, true);
    return x + __int_as_float(y);
}
__device__ __forceinline__ float red16(float x) {
    x = dpp_add_<0xB1>(x);    // quad_perm(1,0,3,2)  = xor 1
    x = dpp_add_<0x4E>(x);    // quad_perm(2,3,0,1)  = xor 2
    x = dpp_add_<0x141>(x);   // row_half_mirror     (combines quads within 8)
    x = dpp_add_<0x140>(x);   // row_mirror          (combines halves within 16)
    return x;
}

// async global->LDS, 16 bytes per lane; LDS dest = wave-uniform base + lane*16
__device__ __forceinline__ void gll16(const ushort_t* g, ushort_t* l) {
    __builtin_amdgcn_global_load_lds(
        (const __attribute__((address_space(1))) uint32_t*)g,
        (__attribute__((address_space(3))) uint32_t*)l, 16, 0, 0);
}

// ---------------------------------------------------------------------------
// bf16 MFMA GEMM (m97 structure): acc = A[M,K] @ W[N,K]^T
// EPI 0: Cb = bf16(acc)
// EPI 1: Cf = acc + e0f[idx]   (f32 residual out; e0f may alias Cf, same idx)
// EPI 2: Cf = gate-blend f32
// ---------------------------------------------------------------------------
template<int EPI>
__global__ __launch_bounds__(256)
void gemm_bf16(const ushort_t* __restrict__ A, int lda,
               const ushort_t* __restrict__ W, int ldw,
               float* __restrict__ Cf, ushort_t* __restrict__ Cb,
               int M, int N, int K,
               const float* __restrict__ e0f,
               const float* __restrict__ e1f,
               const float* __restrict__ e2f)
{
    __shared__ ushort_t As[128 * 32];
    __shared__ ushort_t Bs[128 * 32];
    const int tid = threadIdx.x;
    const int m0 = blockIdx.y * 128;
    const int n0 = blockIdx.x * 128;
    const int lane = tid & 63;
    const int wv = tid >> 6;
    const int wm = (wv >> 1) * 64, wn = (wv & 1) * 64;
    const int lr = lane & 15, lk = lane >> 4;
    const int srow = lane >> 2;
    const int scol = (lane & 3) * 8;

    f32x4 acc[4][4];
#pragma unroll
    for (int i = 0; i < 4; i++)
#pragma unroll
        for (int j = 0; j < 4; j++) acc[i][j] = (f32x4){0.f, 0.f, 0.f, 0.f};

    const ushort_t* Ab = A + (size_t)m0 * lda;
    const ushort_t* Wb = W + (size_t)n0 * ldw;

    for (int k0 = 0; k0 < K; k0 += 32) {
#pragma unroll
        for (int i = 0; i < 2; i++) {
            const int c = wv * 2 + i;
            const int row = c * 16 + srow;
            gll16(Ab + (size_t)row * lda + k0 + scol, &As[c * 512]);
            gll16(Wb + (size_t)row * ldw + k0 + scol, &Bs[c * 512]);
        }
        __syncthreads();
        bf16x8 af[4], bq[4];
#pragma unroll
        for (int mi = 0; mi < 4; mi++)
            af[mi] = *reinterpret_cast<const bf16x8*>(&As[(wm + mi * 16 + lr) * 32 + lk * 8]);
#pragma unroll
        for (int ni = 0; ni < 4; ni++)
            bq[ni] = *reinterpret_cast<const bf16x8*>(&Bs[(wn + ni * 16 + lr) * 32 + lk * 8]);
#pragma unroll
        for (int mi = 0; mi < 4; mi++)
#pragma unroll
            for (int ni = 0; ni < 4; ni++)
                acc[mi][ni] = __builtin_amdgcn_mfma_f32_16x16x32_bf16(af[mi], bq[ni], acc[mi][ni], 0, 0, 0);
        __syncthreads();
    }

#pragma unroll
    for (int mi = 0; mi < 4; mi++) {
#pragma unroll
        for (int ni = 0; ni < 4; ni++) {
            const int col = n0 + wn + ni * 16 + lr;
#pragma unroll
            for (int rr = 0; rr < 4; rr++) {
                const int row = m0 + wm + mi * 16 + lk * 4 + rr;
                const size_t idx = (size_t)row * N + col;
                const float val = acc[mi][ni][rr];
                if (EPI == 0) {
                    Cb[idx] = f2bf(val);
                } else if (EPI == 1) {
                    Cf[idx] = val + e0f[idx];
                } else {
                    const int b = row >> 11;
                    const float gate = sigmoidf_(val + e2f[b * D_ + col]);
                    Cf[idx] = gate * e0f[idx] + (1.f - gate) * e1f[b * D_ + col];
                }
            }
        }
    }
}

// fp32 -> bf16 (float4 per thread)
__global__ __launch_bounds__(256)
void tobf16_kernel(const float* __restrict__ in, ushort_t* __restrict__ out)
{
    const size_t i = (size_t)blockIdx.x * 256 + threadIdx.x;
    const float4 v = reinterpret_cast<const float4*>(in)[i];
    *reinterpret_cast<short4v*>(&out[i * 4]) = pack4(v);
}

// es[b,j] = prev[b,:] . state_proj_w[j,:]  (one wave per output)
__global__ __launch_bounds__(256)
void es_kernel(const float* __restrict__ prev, const float* __restrict__ spw,
               float* __restrict__ es)
{
    const int out = blockIdx.x * 4 + (threadIdx.x >> 6);
    const int lane = threadIdx.x & 63;
    const int b = out >> 10, j = out & 1023;
    const float4* pr = reinterpret_cast<const float4*>(prev + (size_t)b * D_);
    const float4* wr = reinterpret_cast<const float4*>(spw + (size_t)j * D_);
    float acc = 0.f;
#pragma unroll
    for (int p = 0; p < 4; p++) {
        float4 a = pr[lane + 64 * p], w = wr[lane + 64 * p];
        acc += a.x * w.x + a.y * w.y + a.z * w.z + a.w * w.w;
    }
#pragma unroll
    for (int m = 1; m < 64; m <<= 1) acc += __shfl_xor(acc, m);
    if (lane == 0) es[out] = acc;
}

// esg[b,d] = es[b,:] . state_gate_w[d, D:2D] + state_gate_b[d]
__global__ __launch_bounds__(256)
void esg_kernel(const float* __restrict__ es, const float* __restrict__ sgw,
                const float* __restrict__ sgb, float* __restrict__ esg)
{
    const int out = blockIdx.x * 4 + (threadIdx.x >> 6);
    const int lane = threadIdx.x & 63;
    const int b = out >> 10, d = out & 1023;
    const float4* er = reinterpret_cast<const float4*>(es + (size_t)b * D_);
    const float4* wr = reinterpret_cast<const float4*>(sgw + (size_t)d * (2 * D_) + D_);
    float acc = 0.f;
#pragma unroll
    for (int p = 0; p < 4; p++) {
        float4 a = er[lane + 64 * p], w = wr[lane + 64 * p];
        acc += a.x * w.x + a.y * w.y + a.z * w.z + a.w * w.w;
    }
#pragma unroll
    for (int m = 1; m < 64; m <<= 1) acc += __shfl_xor(acc, m);
    if (lane == 0) esg[out] = acc + sgb[d];
}

// RMSNorm rows of 1024, f32 in -> bf16 out
__global__ __launch_bounds__(256)
void rmsnorm_bf16_kernel(const float* __restrict__ x, const float* __restrict__ w,
                         ushort_t* __restrict__ y)
{
    const int row = blockIdx.x;
    const int tid = threadIdx.x;
    const float4 v = reinterpret_cast<const float4*>(x + (size_t)row * D_)[tid];
    float ss = v.x * v.x + v.y * v.y + v.z * v.z + v.w * v.w;
#pragma unroll
    for (int m = 1; m < 64; m <<= 1) ss += __shfl_xor(ss, m);
    __shared__ float red[4];
    if ((tid & 63) == 0) red[tid >> 6] = ss;
    __syncthreads();
    ss = red[0] + red[1] + red[2] + red[3];
    const float rs = rsqrtf(ss * (1.f / 1024.f) + EPS_);
    const float4 wv = reinterpret_cast<const float4*>(w)[tid];
    float4 r;
    r.x = v.x * rs * wv.x; r.y = v.y * rs * wv.y;
    r.z = v.z * rs * wv.z; r.w = v.w * rs * wv.w;
    *reinterpret_cast<short4v*>(&y[(size_t)row * D_ + tid * 4]) = pack4(r);
}

// per-head RMSNorm rows of 256, bf16 in -> bf16 out (one wave per row)
__global__ __launch_bounds__(256)
void onorm_bf16_kernel(const ushort_t* __restrict__ x, const float* __restrict__ w,
                       ushort_t* __restrict__ y)
{
    const int row = blockIdx.x * 4 + (threadIdx.x >> 6);
    const int lane = threadIdx.x & 63;
    const float4 v = cvt4(reinterpret_cast<const short4v*>(x + (size_t)row * 256)[lane]);
    float ss = v.x * v.x + v.y * v.y + v.z * v.z + v.w * v.w;
#pragma unroll
    for (int m = 1; m < 64; m <<= 1) ss += __shfl_xor(ss, m);
    const float rs = rsqrtf(ss * (1.f / 256.f) + EPS_);
    const float4 wv = reinterpret_cast<const float4*>(w)[lane];
    float4 r;
    r.x = v.x * rs * wv.x; r.y = v.y * rs * wv.y;
    r.z = v.z * rs * wv.z; r.w = v.w * rs * wv.w;
    *reinterpret_cast<short4v*>(&y[(size_t)row * 256 + lane * 4]) = pack4(r);
}

// l2 normalize rows of 256 in-place, bf16 (one wave per row)
__global__ __launch_bounds__(256)
void l2n_kernel(ushort_t* __restrict__ x)
{
    const int row = blockIdx.x * 4 + (threadIdx.x >> 6);
    const int lane = threadIdx.x & 63;
    short4v* xr = reinterpret_cast<short4v*>(x + (size_t)row * 256);
    float4 v = cvt4(xr[lane]);
    float ss = v.x * v.x + v.y * v.y + v.z * v.z + v.w * v.w;
#pragma unroll
    for (int m = 1; m < 64; m <<= 1) ss += __shfl_xor(ss, m);
    const float rs = rsqrtf(ss + EPS_);
    v.x *= rs; v.y *= rs; v.z *= rs; v.w *= rs;
    xr[lane] = pack4(v);
}

// causal depthwise conv (K=4) + SiLU, bf16 in/out
__global__ __launch_bounds__(256)
void conv_silu_kernel(const ushort_t* __restrict__ x, const float* __restrict__ w,
                      ushort_t* __restrict__ y, int inC4, int outC4, int outOff4,
                      int chOff4)
{
    const size_t gid = (size_t)blockIdx.x * 256 + threadIdx.x;
    const int c4 = (int)(gid % inC4);
    const size_t bt = gid / inC4;
    const int t = (int)(bt & (T_ - 1));
    const short4v* xr = reinterpret_cast<const short4v*>(x) + bt * inC4 + c4;
    const float4* wr = reinterpret_cast<const float4*>(w) + chOff4 + (size_t)c4 * 4;
    const float4 w0 = wr[0], w1 = wr[1], w2 = wr[2], w3 = wr[3];
    const float4 z = {0.f, 0.f, 0.f, 0.f};
    const float4 x3 = cvt4(xr[0]);
    const float4 x2v = (t >= 1) ? cvt4(xr[-(ptrdiff_t)inC4]) : z;
    const float4 x1v = (t >= 2) ? cvt4(xr[-2 * (ptrdiff_t)inC4]) : z;
    const float4 x0v = (t >= 3) ? cvt4(xr[-3 * (ptrdiff_t)inC4]) : z;
    float4 a;
    a.x = x0v.x * w0.x + x1v.x * w0.y + x2v.x * w0.z + x3.x * w0.w;
    a.y = x0v.y * w1.x + x1v.y * w1.y + x2v.y * w1.z + x3.y * w1.w;
    a.z = x0v.z * w2.x + x1v.z * w2.y + x2v.z * w2.z + x3.z * w2.w;
    a.w = x0v.w * w3.x + x1v.w * w3.y + x2v.w * w3.z + x3.w * w3.w;
    float4 r;
    r.x = siluf_(a.x); r.y = siluf_(a.y); r.z = siluf_(a.z); r.w = siluf_(a.w);
    reinterpret_cast<short4v*>(y)[bt * outC4 + outOff4 + c4] = pack4(r);
}

// beta/g projections (N=12) from bf16 h
__global__ __launch_bounds__(256)
void proj_ba_kernel(const ushort_t* __restrict__ hb, const float* __restrict__ bw,
                    const float* __restrict__ aw, const float* __restrict__ Alog,
                    const float* __restrict__ dtb,
                    float* __restrict__ beta, float* __restrict__ g)
{
    const int row = blockIdx.x;
    const int wv = threadIdx.x >> 6, lane = threadIdx.x & 63;
    const ushort_t* hr = hb + (size_t)row * D_;
#pragma unroll
    for (int s = 0; s < 3; s++) {
        const int o = wv * 3 + s;
        const float* wrow = (o < 8) ? (bw + (size_t)o * D_) : (aw + (size_t)(o - 8) * D_);
        const float4* wr4 = reinterpret_cast<const float4*>(wrow);
        float acc = 0.f;
#pragma unroll
        for (int p = 0; p < 2; p++) {
            const int gg = lane + 64 * p;
            const bf16x8 hv = *reinterpret_cast<const bf16x8*>(&hr[gg * 8]);
            const float4 wa = wr4[gg * 2], wb2 = wr4[gg * 2 + 1];
            acc += bf2f((unsigned short)hv[0]) * wa.x + bf2f((unsigned short)hv[1]) * wa.y
                 + bf2f((unsigned short)hv[2]) * wa.z + bf2f((unsigned short)hv[3]) * wa.w
                 + bf2f((unsigned short)hv[4]) * wb2.x + bf2f((unsigned short)hv[5]) * wb2.y
                 + bf2f((unsigned short)hv[6]) * wb2.z + bf2f((unsigned short)hv[7]) * wb2.w;
        }
#pragma unroll
        for (int m = 1; m < 64; m <<= 1) acc += __shfl_xor(acc, m);
        if (lane == 0) {
            if (o < 8) {
                beta[(size_t)row * 8 + o] = 2.f * sigmoidf_(acc);
            } else {
                const int hh = o - 8;
                const float xg = acc + dtb[hh];
                const float sp = (xg > 20.f) ? xg : log1pf(expf(xg));
                g[(size_t)row * 4 + hh] = -expf(Alog[hh]) * sp;
            }
        }
    }
}

// ---------------------------------------------------------------------------
// sequential gated delta-product scan, v3:
//  - group-staged GT=8, T14 async split (unchanged from v2)
//  - DPP-based 16-lane reduce (no ds_swizzle -> LDS in-order queue never
//    stalls the token chain; compiler can pipeline ds_reads across tokens)
//  - group-start scalar prefetch of g/beta/v into registers; exp off-chain
//  - decay fused into pred scaling + S-update FMA (no separate decay pass)
// ---------------------------------------------------------------------------
#define GT 8
__global__ __launch_bounds__(256)
void scan_kernel(const ushort_t* __restrict__ q, const ushort_t* __restrict__ k,
                 const ushort_t* __restrict__ v, const float* __restrict__ beta,
                 const float* __restrict__ g, ushort_t* __restrict__ o)
{
    // XCD-bijective remap: 16 dv-chunks of (b,h) -> same (d mod 8)
    const int d = blockIdx.x;
    const int m = d >> 3;
    const int bh = (d & 7) * 4 + (m >> 4);
    const int dvc = m & 15;
    const int b = bh >> 2, h = bh & 3;
    const int dv0 = dvc * 16;
    const int tid = threadIdx.x;
    const int kk = tid & 15;
    const int dvl = tid >> 4;

    __shared__ __align__(16) float sQ[2][GT][320];
    __shared__ __align__(16) float sK[2][GT][2][320];
    __shared__ __align__(16) float sV[2][GT][2][16];
    __shared__ float sB[2][GT][2];
    __shared__ float sG[2][GT];

    float S[16];
#pragma unroll
    for (int j = 0; j < 16; j++) S[j] = 0.f;

    const size_t bT = (size_t)b * T_;

    // staging registers (global -> reg early, reg -> LDS late)
    short4v rq0, rq1, rk00, rk01, rk10, rk11, rv0, rv1;
    float rb = 0.f, rg = 0.f;

    auto stage_load = [&](int grp) {
        const size_t t0 = bT + (size_t)grp * GT;
        {
            const int tq = tid >> 5, e = (tid & 31) * 8;
            const ushort_t* qp = q + ((t0 + tq) * 4 + h) * 256 + e;
            rq0 = *reinterpret_cast<const short4v*>(qp);
            rq1 = *reinterpret_cast<const short4v*>(qp + 4);
        }
        {
            const int idx = tid * 8;
            const int tk = idx >> 9, ii = (idx >> 8) & 1, e = idx & 255;
            const ushort_t* kp = k + (((t0 + tk) * 2 + ii) * 4 + h) * 256 + e;
            rk00 = *reinterpret_cast<const short4v*>(kp);
            rk01 = *reinterpret_cast<const short4v*>(kp + 4);
        }
        {
            const int idx = 2048 + tid * 8;
            const int tk = idx >> 9, ii = (idx >> 8) & 1, e = idx & 255;
            const ushort_t* kp = k + (((t0 + tk) * 2 + ii) * 4 + h) * 256 + e;
            rk10 = *reinterpret_cast<const short4v*>(kp);
            rk11 = *reinterpret_cast<const short4v*>(kp + 4);
        }
        if (tid < 32) {
            const int tv = tid >> 2, ii = (tid >> 1) & 1, e8 = (tid & 1) * 8;
            const ushort_t* vp = v + (((t0 + tv) * 2 + ii) * 4 + h) * 256 + dv0 + e8;
            rv0 = *reinterpret_cast<const short4v*>(vp);
            rv1 = *reinterpret_cast<const short4v*>(vp + 4);
        }
        if (tid < 16) rb = beta[(t0 + (tid >> 1)) * 8 + (tid & 1) * 4 + h];
        else if (tid < 24) rg = g[(t0 + (tid - 16)) * 4 + h];
    };

    auto stage_write = [&](int bufi) {
        {
            const int tq = tid >> 5, e = (tid & 31) * 8;
            float* dst = &sQ[bufi][tq][(e >> 4) * 20 + (e & 15)];
            *reinterpret_cast<float4*>(dst) = cvt4(rq0);
            *reinterpret_cast<float4*>(dst + 4) = cvt4(rq1);
        }
        {
            const int idx = tid * 8;
            const int tk = idx >> 9, ii = (idx >> 8) & 1, e = idx & 255;
            float* dst = &sK[bufi][tk][ii][(e >> 4) * 20 + (e & 15)];
            *reinterpret_cast<float4*>(dst) = cvt4(rk00);
            *reinterpret_cast<float4*>(dst + 4) = cvt4(rk01);
        }
        {
            const int idx = 2048 + tid * 8;
            const int tk = idx >> 9, ii = (idx >> 8) & 1, e = idx & 255;
            float* dst = &sK[bufi][tk][ii][(e >> 4) * 20 + (e & 15)];
            *reinterpret_cast<float4*>(dst) = cvt4(rk10);
            *reinterpret_cast<float4*>(dst + 4) = cvt4(rk11);
        }
        if (tid < 32) {
            const int tv = tid >> 2, ii = (tid >> 1) & 1, e8 = (tid & 1) * 8;
            float* dst = &sV[bufi][tv][ii][e8];
            *reinterpret_cast<float4*>(dst) = cvt4(rv0);
            *reinterpret_cast<float4*>(dst + 4) = cvt4(rv1);
        }
        if (tid < 16) sB[bufi][tid >> 1][tid & 1] = rb;
        else if (tid < 24) sG[bufi][tid - 16] = rg;
    };

    stage_load(0);
    stage_write(0);
    __syncthreads();
    int buf = 0;
    const int NG = T_ / GT;
    for (int grp = 0; grp < NG; ++grp) {
        if (grp + 1 < NG) stage_load(grp + 1);   // HBM latency hides under compute

        // group-start scalar prefetch (constant-indexed after unroll)
        float dec[GT], bb0[GT], bb1[GT], vv0[GT], vv1[GT];
#pragma unroll
        for (int tt = 0; tt < GT; ++tt) {
            dec[tt] = __expf(sG[buf][tt]);
            bb0[tt] = sB[buf][tt][0];
            bb1[tt] = sB[buf][tt][1];
            vv0[tt] = sV[buf][tt][0][dvl];
            vv1[tt] = sV[buf][tt][1][dvl];
        }

#pragma unroll
        for (int tt = 0; tt < GT; ++tt) {
            const float dtt = dec[tt];
            // ---- i = 0 (decay fused) ----
            const float* kp0 = &sK[buf][tt][0][kk * 20];
            const float4 a0 = *reinterpret_cast<const float4*>(kp0);
            const float4 a1 = *reinterpret_cast<const float4*>(kp0 + 4);
            const float4 a2 = *reinterpret_cast<const float4*>(kp0 + 8);
            const float4 a3 = *reinterpret_cast<const float4*>(kp0 + 12);
            float p0 = S[0]*a0.x + S[1]*a0.y + S[2]*a0.z + S[3]*a0.w;
            float p1 = S[4]*a1.x + S[5]*a1.y + S[6]*a1.z + S[7]*a1.w;
            float p2 = S[8]*a2.x + S[9]*a2.y + S[10]*a2.z + S[11]*a2.w;
            float p3 = S[12]*a3.x + S[13]*a3.y + S[14]*a3.z + S[15]*a3.w;
            const float pred0 = red16((p0 + p1) + (p2 + p3)) * dtt;
            const float u0 = (vv0[tt] - pred0) * bb0[tt];
            // S = dec*S + k0*u0  (fused decay)
            S[0]  = fmaf(S[0],  dtt, a0.x * u0);
            S[1]  = fmaf(S[1],  dtt, a0.y * u0);
            S[2]  = fmaf(S[2],  dtt, a0.z * u0);
            S[3]  = fmaf(S[3],  dtt, a0.w * u0);
            S[4]  = fmaf(S[4],  dtt, a1.x * u0);
            S[5]  = fmaf(S[5],  dtt, a1.y * u0);
            S[6]  = fmaf(S[6],  dtt, a1.z * u0);
            S[7]  = fmaf(S[7],  dtt, a1.w * u0);
            S[8]  = fmaf(S[8],  dtt, a2.x * u0);
            S[9]  = fmaf(S[9],  dtt, a2.y * u0);
            S[10] = fmaf(S[10], dtt, a2.z * u0);
            S[11] = fmaf(S[11], dtt, a2.w * u0);
            S[12] = fmaf(S[12], dtt, a3.x * u0);
            S[13] = fmaf(S[13], dtt, a3.y * u0);
            S[14] = fmaf(S[14], dtt, a3.z * u0);
            S[15] = fmaf(S[15], dtt, a3.w * u0);
            // ---- i = 1 ----
            const float* kp1 = &sK[buf][tt][1][kk * 20];
            const float4 b0 = *reinterpret_cast<const float4*>(kp1);
            const float4 b1 = *reinterpret_cast<const float4*>(kp1 + 4);
            const float4 b2 = *reinterpret_cast<const float4*>(kp1 + 8);
            const float4 b3 = *reinterpret_cast<const float4*>(kp1 + 12);
            p0 = S[0]*b0.x + S[1]*b0.y + S[2]*b0.z + S[3]*b0.w;
            p1 = S[4]*b1.x + S[5]*b1.y + S[6]*b1.z + S[7]*b1.w;
            p2 = S[8]*b2.x + S[9]*b2.y + S[10]*b2.z + S[11]*b2.w;
            p3 = S[12]*b3.x + S[13]*b3.y + S[14]*b3.z + S[15]*b3.w;
            const float pred1 = red16((p0 + p1) + (p2 + p3));
            const float u1 = (vv1[tt] - pred1) * bb1[tt];
            S[0]  += b0.x * u1;  S[1]  += b0.y * u1;
            S[2]  += b0.z * u1;  S[3]  += b0.w * u1;
            S[4]  += b1.x * u1;  S[5]  += b1.y * u1;
            S[6]  += b1.z * u1;  S[7]  += b1.w * u1;
            S[8]  += b2.x * u1;  S[9]  += b2.y * u1;
            S[10] += b2.z * u1;  S[11] += b2.w * u1;
            S[12] += b3.x * u1;  S[13] += b3.y * u1;
            S[14] += b3.z * u1;  S[15] += b3.w * u1;
            // ---- output ----
            const float* qp = &sQ[buf][tt][kk * 20];
            const float4 q0 = *reinterpret_cast<const float4*>(qp);
            const float4 q1 = *reinterpret_cast<const float4*>(qp + 4);
            const float4 q2 = *reinterpret_cast<const float4*>(qp + 8);
            const float4 q3 = *reinterpret_cast<const float4*>(qp + 12);
            float o0 = S[0]*q0.x + S[1]*q0.y + S[2]*q0.z + S[3]*q0.w;
            float o1 = S[4]*q1.x + S[5]*q1.y + S[6]*q1.z + S[7]*q1.w;
            float o2 = S[8]*q2.x + S[9]*q2.y + S[10]*q2.z + S[11]*q2.w;
            float o3 = S[12]*q3.x + S[13]*q3.y + S[14]*q3.z + S[15]*q3.w;
            const float op = red16((o0 + o1) + (o2 + o3));
            if (kk == 0)
                o[((bT + (size_t)grp * GT + tt) * 4 + h) * 256 + dv0 + dvl] = f2bf(op * 0.0625f);
        }
        if (grp + 1 < NG) stage_write(buf ^ 1);  // after compute: loads landed
        __syncthreads();
        buf ^= 1;
    }
}

// silu(g)*u on bf16, in-place into g buffer (4 elems per thread)
__global__ __launch_bounds__(256)
void silu_mul_kernel(ushort_t* __restrict__ gb, const ushort_t* __restrict__ ub)
{
    const size_t i = (size_t)blockIdx.x * 256 + threadIdx.x;
    const float4 gv = cvt4(reinterpret_cast<short4v*>(gb)[i]);
    const float4 uv = cvt4(reinterpret_cast<const short4v*>(ub)[i]);
    float4 r;
    r.x = siluf_(gv.x) * uv.x; r.y = siluf_(gv.y) * uv.y;
    r.z = siluf_(gv.z) * uv.z; r.w = siluf_(gv.w) * uv.w;
    reinterpret_cast<short4v*>(gb)[i] = pack4(r);
}

// copy out[:, T-1, :] to tail of d_out
__global__ __launch_bounds__(256)
void tail_kernel(float* __restrict__ out)
{
    const int i = blockIdx.x * 256 + threadIdx.x;
    const int b = i >> 10, d = i & 1023;
    out[(size_t)B_ * T_ * D_ + i] = out[((size_t)b * T_ + (T_ - 1)) * D_ + d];
}

// ---------------------------------------------------------------------------
extern "C" void kernel_launch(void* const* d_in, const int* in_sizes, int n_in,
                              void* d_out, int out_size, void* d_ws, size_t ws_size,
                              hipStream_t stream)
{
    const float* x    = (const float*)d_in[0];
    const float* prev = (const float*)d_in[1];
    const float* spw  = (const float*)d_in[2];
    const float* sgw  = (const float*)d_in[3];
    const float* sgb  = (const float*)d_in[4];
    const float* anw  = (const float*)d_in[5];
    const float* qw   = (const float*)d_in[6];
    const float* kw   = (const float*)d_in[7];
    const float* vw   = (const float*)d_in[8];
    const float* bw   = (const float*)d_in[9];
    const float* aw   = (const float*)d_in[10];
    const float* Alog = (const float*)d_in[11];
    const float* dtb  = (const float*)d_in[12];
    const float* qcw  = (const float*)d_in[13];
    const float* kcw  = (const float*)d_in[14];
    const float* vcw  = (const float*)d_in[15];
    const float* onw  = (const float*)d_in[16];
    const float* ow   = (const float*)d_in[17];
    const float* mnw  = (const float*)d_in[18];
    const float* gw   = (const float*)d_in[19];
    const float* uw   = (const float*)d_in[20];
    const float* dw   = (const float*)d_in[21];
    float* out = (float*)d_out;

    const size_t NX = (size_t)B_ * T_ * D_;   // 16,777,216
    const int M = B_ * T_;                    // 16384
    const size_t MI = (size_t)M * I_;         // 46,137,344

    // ---- workspace layout (shorts), peak ~242 MB ----
    ushort_t* wsb = (ushort_t*)d_ws;
    size_t off = 0;
    ushort_t* wsc = wsb + off; off += 2883584;   // weight scratch (max I_*D_)
    ushort_t* hb  = wsb + off; off += NX;        // hb / onb / h2b
    ushort_t* raw = wsb + off; off += NX;        // pre-conv chunk; later ob
    ushort_t* qb  = wsb + off; off += NX;
    ushort_t* kb  = wsb + off; off += 2 * NX;    // also hosts xb early
    ushort_t* vb  = wsb + off; off += 2 * NX;
    float*    es   = (float*)(wsb + off);
    float*    esg  = es + (size_t)B_ * D_;
    float*    beta = esg + (size_t)B_ * D_;
    float*    gbuf = beta + (size_t)M * 8;
    // overlays
    ushort_t* xb  = kb;        // bf16(x) for gate GEMM (dead before conv fills kb)
    ushort_t* ob  = raw;       // scan output (raw dead after convs)
    ushort_t* mgb = raw;       // MLP: MI shorts over raw+qb+kb (dead post-scan)
    ushort_t* mub = raw + MI;  // MI shorts, ends within vb
    float*    xf  = out;       // f32 residual stream lives in d_out

    // ---- state fusion ----
    tobf16_kernel<<<(int)(NX / 1024), 256, 0, stream>>>(x, xb);
    tobf16_kernel<<<2048, 256, 0, stream>>>(sgw, wsc);
    es_kernel<<<2048, 256, 0, stream>>>(prev, spw, es);
    esg_kernel<<<2048, 256, 0, stream>>>(es, sgw, sgb, esg);
    gemm_bf16<2><<<dim3(8, 128), 256, 0, stream>>>(
        xb, D_, wsc, 2 * D_, xf, nullptr, M, D_, D_, x, es, esg);

    // ---- attention sub-block ----
    rmsnorm_bf16_kernel<<<M, 256, 0, stream>>>(xf, anw, hb);
    proj_ba_kernel<<<M, 256, 0, stream>>>(hb, bw, aw, Alog, dtb, beta, gbuf);

    // q: one N=1024 chunk
    tobf16_kernel<<<1024, 256, 0, stream>>>(qw, wsc);
    gemm_bf16<0><<<dim3(8, 128), 256, 0, stream>>>(
        hb, D_, wsc, D_, nullptr, raw, M, 1024, D_, nullptr, nullptr, nullptr);
    conv_silu_kernel<<<16384, 256, 0, stream>>>(raw, qcw, qb, 256, 256, 0, 0);

    // k: two N=1024 chunks
    tobf16_kernel<<<2048, 256, 0, stream>>>(kw, wsc);
    for (int j = 0; j < 2; j++) {
        gemm_bf16<0><<<dim3(8, 128), 256, 0, stream>>>(
            hb, D_, wsc + (size_t)j * 1024 * D_, D_, nullptr, raw, M, 1024, D_,
            nullptr, nullptr, nullptr);
        conv_silu_kernel<<<16384, 256, 0, stream>>>(raw, kcw, kb, 256, 512, j * 256, j * 1024);
    }

    // v: two N=1024 chunks
    tobf16_kernel<<<2048, 256, 0, stream>>>(vw, wsc);
    for (int j = 0; j < 2; j++) {
        gemm_bf16<0><<<dim3(8, 128), 256, 0, stream>>>(
            hb, D_, wsc + (size_t)j * 1024 * D_, D_, nullptr, raw, M, 1024, D_,
            nullptr, nullptr, nullptr);
        conv_silu_kernel<<<16384, 256, 0, stream>>>(raw, vcw, vb, 256, 512, j * 256, j * 1024);
    }

    l2n_kernel<<<16384, 256, 0, stream>>>(qb);
    l2n_kernel<<<32768, 256, 0, stream>>>(kb);

    scan_kernel<<<512, 256, 0, stream>>>(qb, kb, vb, beta, gbuf, ob);

    onorm_bf16_kernel<<<16384, 256, 0, stream>>>(ob, onw, hb);
    tobf16_kernel<<<1024, 256, 0, stream>>>(ow, wsc);
    gemm_bf16<1><<<dim3(8, 128), 256, 0, stream>>>(
        hb, D_, wsc, D_, out, nullptr, M, 1024, D_, xf, nullptr, nullptr);

    // ---- MLP sub-block ----
    rmsnorm_bf16_kernel<<<M, 256, 0, stream>>>(out, mnw, hb);
    tobf16_kernel<<<2816, 256, 0, stream>>>(gw, wsc);
    gemm_bf16<0><<<dim3(22, 128), 256, 0, stream>>>(
        hb, D_, wsc, D_, nullptr, mgb, M, I_, D_, nullptr, nullptr, nullptr);
    tobf16_kernel<<<2816, 256, 0, stream>>>(uw, wsc);
    gemm_bf16<0><<<dim3(22, 128), 256, 0, stream>>>(
        hb, D_, wsc, D_, nullptr, mub, M, I_, D_, nullptr, nullptr, nullptr);
    silu_mul_kernel<<<(int)((MI / 4) / 256), 256, 0, stream>>>(mgb, mub);
    tobf16_kernel<<<2816, 256, 0, stream>>>(dw, wsc);
    gemm_bf16<1><<<dim3(8, 128), 256, 0, stream>>>(
        mgb, I_, wsc, I_, out, nullptr, M, 1024, I_, out, nullptr, nullptr);

    tail_kernel<<<32, 256, 0, stream>>>(out);
}

// Round 9
// 2439.346 us; speedup vs baseline: 2.1041x; 1.1479x over previous
//
#include <hip/hip_runtime.h>
#include <stdint.h>

#define B_ 8
#define T_ 2048
#define D_ 1024
#define H_ 4
#define DK_ 256
#define DV_ 256
#define NH_ 2
#define I_ 2816
#define EPS_ 1e-6f

typedef __attribute__((ext_vector_type(4))) short short4v;
typedef __attribute__((ext_vector_type(8))) short bf16x8;
typedef __attribute__((ext_vector_type(4))) float f32x4;
typedef __attribute__((ext_vector_type(2))) float f32x2;
typedef unsigned short ushort_t;

__device__ __forceinline__ unsigned short f2bf(float f) {
    union { float f; unsigned int u; } c; c.f = f;
    unsigned int r = c.u + 0x7FFFu + ((c.u >> 16) & 1u);
    return (unsigned short)(r >> 16);
}
__device__ __forceinline__ float bf2f(unsigned short s) {
    union { unsigned int u; float f; } c; c.u = ((unsigned int)s) << 16;
    return c.f;
}
__device__ __forceinline__ short4v pack4(float4 v) {
    short4v r;
    r.x = (short)f2bf(v.x); r.y = (short)f2bf(v.y);
    r.z = (short)f2bf(v.z); r.w = (short)f2bf(v.w);
    return r;
}
__device__ __forceinline__ float4 cvt4(short4v s) {
    float4 r;
    r.x = bf2f((unsigned short)s.x); r.y = bf2f((unsigned short)s.y);
    r.z = bf2f((unsigned short)s.z); r.w = bf2f((unsigned short)s.w);
    return r;
}
__device__ __forceinline__ float sigmoidf_(float x) { return 1.f / (1.f + __expf(-x)); }
__device__ __forceinline__ float siluf_(float x)    { return x / (1.f + __expf(-x)); }

// VALU cross-lane reduce over aligned 16-lane groups (DPP rows) — no LDS ops.
template<int CTRL>
__device__ __forceinline__ float dpp_add_(float x) {
    int y = __builtin_amdgcn_update_dpp(0, __float_as_int(x), CTRL, 0xf, 0xf, true);
    return x + __int_as_float(y);
}
__device__ __forceinline__ float red16(float x) {
    x = dpp_add_<0xB1>(x);    // quad_perm(1,0,3,2)  = xor 1
    x = dpp_add_<0x4E>(x);    // quad_perm(2,3,0,1)  = xor 2
    x = dpp_add_<0x141>(x);   // row_half_mirror
    x = dpp_add_<0x140>(x);   // row_mirror
    return x;
}

// async global->LDS, 16 bytes per lane; LDS dest = wave-uniform base + lane*16
__device__ __forceinline__ void gll16(const ushort_t* g, ushort_t* l) {
    __builtin_amdgcn_global_load_lds(
        (const __attribute__((address_space(1))) uint32_t*)g,
        (__attribute__((address_space(3))) uint32_t*)l, 16, 0, 0);
}

// ---------------------------------------------------------------------------
// bf16 MFMA GEMM (m97 structure): acc = A[M,K] @ W[N,K]^T
// EPI 0: Cb = bf16(acc)
// EPI 1: Cf = acc + e0f[idx]   (f32 residual out; e0f may alias Cf, same idx)
// EPI 2: Cf = gate-blend f32
// ---------------------------------------------------------------------------
template<int EPI>
__global__ __launch_bounds__(256)
void gemm_bf16(const ushort_t* __restrict__ A, int lda,
               const ushort_t* __restrict__ W, int ldw,
               float* __restrict__ Cf, ushort_t* __restrict__ Cb,
               int M, int N, int K,
               const float* __restrict__ e0f,
               const float* __restrict__ e1f,
               const float* __restrict__ e2f)
{
    __shared__ ushort_t As[128 * 32];
    __shared__ ushort_t Bs[128 * 32];
    const int tid = threadIdx.x;
    const int m0 = blockIdx.y * 128;
    const int n0 = blockIdx.x * 128;
    const int lane = tid & 63;
    const int wv = tid >> 6;
    const int wm = (wv >> 1) * 64, wn = (wv & 1) * 64;
    const int lr = lane & 15, lk = lane >> 4;
    const int srow = lane >> 2;
    const int scol = (lane & 3) * 8;

    f32x4 acc[4][4];
#pragma unroll
    for (int i = 0; i < 4; i++)
#pragma unroll
        for (int j = 0; j < 4; j++) acc[i][j] = (f32x4){0.f, 0.f, 0.f, 0.f};

    const ushort_t* Ab = A + (size_t)m0 * lda;
    const ushort_t* Wb = W + (size_t)n0 * ldw;

    for (int k0 = 0; k0 < K; k0 += 32) {
#pragma unroll
        for (int i = 0; i < 2; i++) {
            const int c = wv * 2 + i;
            const int row = c * 16 + srow;
            gll16(Ab + (size_t)row * lda + k0 + scol, &As[c * 512]);
            gll16(Wb + (size_t)row * ldw + k0 + scol, &Bs[c * 512]);
        }
        __syncthreads();
        bf16x8 af[4], bq[4];
#pragma unroll
        for (int mi = 0; mi < 4; mi++)
            af[mi] = *reinterpret_cast<const bf16x8*>(&As[(wm + mi * 16 + lr) * 32 + lk * 8]);
#pragma unroll
        for (int ni = 0; ni < 4; ni++)
            bq[ni] = *reinterpret_cast<const bf16x8*>(&Bs[(wn + ni * 16 + lr) * 32 + lk * 8]);
#pragma unroll
        for (int mi = 0; mi < 4; mi++)
#pragma unroll
            for (int ni = 0; ni < 4; ni++)
                acc[mi][ni] = __builtin_amdgcn_mfma_f32_16x16x32_bf16(af[mi], bq[ni], acc[mi][ni], 0, 0, 0);
        __syncthreads();
    }

#pragma unroll
    for (int mi = 0; mi < 4; mi++) {
#pragma unroll
        for (int ni = 0; ni < 4; ni++) {
            const int col = n0 + wn + ni * 16 + lr;
#pragma unroll
            for (int rr = 0; rr < 4; rr++) {
                const int row = m0 + wm + mi * 16 + lk * 4 + rr;
                const size_t idx = (size_t)row * N + col;
                const float val = acc[mi][ni][rr];
                if (EPI == 0) {
                    Cb[idx] = f2bf(val);
                } else if (EPI == 1) {
                    Cf[idx] = val + e0f[idx];
                } else {
                    const int b = row >> 11;
                    const float gate = sigmoidf_(val + e2f[b * D_ + col]);
                    Cf[idx] = gate * e0f[idx] + (1.f - gate) * e1f[b * D_ + col];
                }
            }
        }
    }
}

// fp32 -> bf16 (float4 per thread)
__global__ __launch_bounds__(256)
void tobf16_kernel(const float* __restrict__ in, ushort_t* __restrict__ out)
{
    const size_t i = (size_t)blockIdx.x * 256 + threadIdx.x;
    const float4 v = reinterpret_cast<const float4*>(in)[i];
    *reinterpret_cast<short4v*>(&out[i * 4]) = pack4(v);
}

// es[b,j] = prev[b,:] . state_proj_w[j,:]  (one wave per output)
__global__ __launch_bounds__(256)
void es_kernel(const float* __restrict__ prev, const float* __restrict__ spw,
               float* __restrict__ es)
{
    const int out = blockIdx.x * 4 + (threadIdx.x >> 6);
    const int lane = threadIdx.x & 63;
    const int b = out >> 10, j = out & 1023;
    const float4* pr = reinterpret_cast<const float4*>(prev + (size_t)b * D_);
    const float4* wr = reinterpret_cast<const float4*>(spw + (size_t)j * D_);
    float acc = 0.f;
#pragma unroll
    for (int p = 0; p < 4; p++) {
        float4 a = pr[lane + 64 * p], w = wr[lane + 64 * p];
        acc += a.x * w.x + a.y * w.y + a.z * w.z + a.w * w.w;
    }
#pragma unroll
    for (int m = 1; m < 64; m <<= 1) acc += __shfl_xor(acc, m);
    if (lane == 0) es[out] = acc;
}

// esg[b,d] = es[b,:] . state_gate_w[d, D:2D] + state_gate_b[d]
__global__ __launch_bounds__(256)
void esg_kernel(const float* __restrict__ es, const float* __restrict__ sgw,
                const float* __restrict__ sgb, float* __restrict__ esg)
{
    const int out = blockIdx.x * 4 + (threadIdx.x >> 6);
    const int lane = threadIdx.x & 63;
    const int b = out >> 10, d = out & 1023;
    const float4* er = reinterpret_cast<const float4*>(es + (size_t)b * D_);
    const float4* wr = reinterpret_cast<const float4*>(sgw + (size_t)d * (2 * D_) + D_);
    float acc = 0.f;
#pragma unroll
    for (int p = 0; p < 4; p++) {
        float4 a = er[lane + 64 * p], w = wr[lane + 64 * p];
        acc += a.x * w.x + a.y * w.y + a.z * w.z + a.w * w.w;
    }
#pragma unroll
    for (int m = 1; m < 64; m <<= 1) acc += __shfl_xor(acc, m);
    if (lane == 0) esg[out] = acc + sgb[d];
}

// RMSNorm rows of 1024, f32 in -> bf16 out
__global__ __launch_bounds__(256)
void rmsnorm_bf16_kernel(const float* __restrict__ x, const float* __restrict__ w,
                         ushort_t* __restrict__ y)
{
    const int row = blockIdx.x;
    const int tid = threadIdx.x;
    const float4 v = reinterpret_cast<const float4*>(x + (size_t)row * D_)[tid];
    float ss = v.x * v.x + v.y * v.y + v.z * v.z + v.w * v.w;
#pragma unroll
    for (int m = 1; m < 64; m <<= 1) ss += __shfl_xor(ss, m);
    __shared__ float red[4];
    if ((tid & 63) == 0) red[tid >> 6] = ss;
    __syncthreads();
    ss = red[0] + red[1] + red[2] + red[3];
    const float rs = rsqrtf(ss * (1.f / 1024.f) + EPS_);
    const float4 wv = reinterpret_cast<const float4*>(w)[tid];
    float4 r;
    r.x = v.x * rs * wv.x; r.y = v.y * rs * wv.y;
    r.z = v.z * rs * wv.z; r.w = v.w * rs * wv.w;
    *reinterpret_cast<short4v*>(&y[(size_t)row * D_ + tid * 4]) = pack4(r);
}

// per-head RMSNorm rows of 256, bf16 in -> bf16 out (one wave per row)
__global__ __launch_bounds__(256)
void onorm_bf16_kernel(const ushort_t* __restrict__ x, const float* __restrict__ w,
                       ushort_t* __restrict__ y)
{
    const int row = blockIdx.x * 4 + (threadIdx.x >> 6);
    const int lane = threadIdx.x & 63;
    const float4 v = cvt4(reinterpret_cast<const short4v*>(x + (size_t)row * 256)[lane]);
    float ss = v.x * v.x + v.y * v.y + v.z * v.z + v.w * v.w;
#pragma unroll
    for (int m = 1; m < 64; m <<= 1) ss += __shfl_xor(ss, m);
    const float rs = rsqrtf(ss * (1.f / 256.f) + EPS_);
    const float4 wv = reinterpret_cast<const float4*>(w)[lane];
    float4 r;
    r.x = v.x * rs * wv.x; r.y = v.y * rs * wv.y;
    r.z = v.z * rs * wv.z; r.w = v.w * rs * wv.w;
    *reinterpret_cast<short4v*>(&y[(size_t)row * 256 + lane * 4]) = pack4(r);
}

// l2 normalize rows of 256 in-place, bf16 (one wave per row)
__global__ __launch_bounds__(256)
void l2n_kernel(ushort_t* __restrict__ x)
{
    const int row = blockIdx.x * 4 + (threadIdx.x >> 6);
    const int lane = threadIdx.x & 63;
    short4v* xr = reinterpret_cast<short4v*>(x + (size_t)row * 256);
    float4 v = cvt4(xr[lane]);
    float ss = v.x * v.x + v.y * v.y + v.z * v.z + v.w * v.w;
#pragma unroll
    for (int m = 1; m < 64; m <<= 1) ss += __shfl_xor(ss, m);
    const float rs = rsqrtf(ss + EPS_);
    v.x *= rs; v.y *= rs; v.z *= rs; v.w *= rs;
    xr[lane] = pack4(v);
}

// causal depthwise conv (K=4) + SiLU, bf16 in/out
__global__ __launch_bounds__(256)
void conv_silu_kernel(const ushort_t* __restrict__ x, const float* __restrict__ w,
                      ushort_t* __restrict__ y, int inC4, int outC4, int outOff4,
                      int chOff4)
{
    const size_t gid = (size_t)blockIdx.x * 256 + threadIdx.x;
    const int c4 = (int)(gid % inC4);
    const size_t bt = gid / inC4;
    const int t = (int)(bt & (T_ - 1));
    const short4v* xr = reinterpret_cast<const short4v*>(x) + bt * inC4 + c4;
    const float4* wr = reinterpret_cast<const float4*>(w) + chOff4 + (size_t)c4 * 4;
    const float4 w0 = wr[0], w1 = wr[1], w2 = wr[2], w3 = wr[3];
    const float4 z = {0.f, 0.f, 0.f, 0.f};
    const float4 x3 = cvt4(xr[0]);
    const float4 x2v = (t >= 1) ? cvt4(xr[-(ptrdiff_t)inC4]) : z;
    const float4 x1v = (t >= 2) ? cvt4(xr[-2 * (ptrdiff_t)inC4]) : z;
    const float4 x0v = (t >= 3) ? cvt4(xr[-3 * (ptrdiff_t)inC4]) : z;
    float4 a;
    a.x = x0v.x * w0.x + x1v.x * w0.y + x2v.x * w0.z + x3.x * w0.w;
    a.y = x0v.y * w1.x + x1v.y * w1.y + x2v.y * w1.z + x3.y * w1.w;
    a.z = x0v.z * w2.x + x1v.z * w2.y + x2v.z * w2.z + x3.z * w2.w;
    a.w = x0v.w * w3.x + x1v.w * w3.y + x2v.w * w3.z + x3.w * w3.w;
    float4 r;
    r.x = siluf_(a.x); r.y = siluf_(a.y); r.z = siluf_(a.z); r.w = siluf_(a.w);
    reinterpret_cast<short4v*>(y)[bt * outC4 + outOff4 + c4] = pack4(r);
}

// beta/g projections (N=12) from bf16 h
__global__ __launch_bounds__(256)
void proj_ba_kernel(const ushort_t* __restrict__ hb, const float* __restrict__ bw,
                    const float* __restrict__ aw, const float* __restrict__ Alog,
                    const float* __restrict__ dtb,
                    float* __restrict__ beta, float* __restrict__ g)
{
    const int row = blockIdx.x;
    const int wv = threadIdx.x >> 6, lane = threadIdx.x & 63;
    const ushort_t* hr = hb + (size_t)row * D_;
#pragma unroll
    for (int s = 0; s < 3; s++) {
        const int o = wv * 3 + s;
        const float* wrow = (o < 8) ? (bw + (size_t)o * D_) : (aw + (size_t)(o - 8) * D_);
        const float4* wr4 = reinterpret_cast<const float4*>(wrow);
        float acc = 0.f;
#pragma unroll
        for (int p = 0; p < 2; p++) {
            const int gg = lane + 64 * p;
            const bf16x8 hv = *reinterpret_cast<const bf16x8*>(&hr[gg * 8]);
            const float4 wa = wr4[gg * 2], wb2 = wr4[gg * 2 + 1];
            acc += bf2f((unsigned short)hv[0]) * wa.x + bf2f((unsigned short)hv[1]) * wa.y
                 + bf2f((unsigned short)hv[2]) * wa.z + bf2f((unsigned short)hv[3]) * wa.w
                 + bf2f((unsigned short)hv[4]) * wb2.x + bf2f((unsigned short)hv[5]) * wb2.y
                 + bf2f((unsigned short)hv[6]) * wb2.z + bf2f((unsigned short)hv[7]) * wb2.w;
        }
#pragma unroll
        for (int m = 1; m < 64; m <<= 1) acc += __shfl_xor(acc, m);
        if (lane == 0) {
            if (o < 8) {
                beta[(size_t)row * 8 + o] = 2.f * sigmoidf_(acc);
            } else {
                const int hh = o - 8;
                const float xg = acc + dtb[hh];
                const float sp = (xg > 20.f) ? xg : log1pf(expf(xg));
                g[(size_t)row * 4 + hh] = -expf(Alog[hh]) * sp;
            }
        }
    }
}

// ---------------------------------------------------------------------------
// sequential gated delta-product scan, v4: v3 + packed-f32 math.
// All dots / state updates on f32x2 -> v_pk_fma_f32 / v_pk_mul_f32 (2 f32
// per VALU inst) — halves the FMA issue count of the issue-bound token body.
// ---------------------------------------------------------------------------
#define GT 8
__global__ __launch_bounds__(256)
void scan_kernel(const ushort_t* __restrict__ q, const ushort_t* __restrict__ k,
                 const ushort_t* __restrict__ v, const float* __restrict__ beta,
                 const float* __restrict__ g, ushort_t* __restrict__ o)
{
    // XCD-bijective remap: 16 dv-chunks of (b,h) -> same (d mod 8)
    const int d = blockIdx.x;
    const int m = d >> 3;
    const int bh = (d & 7) * 4 + (m >> 4);
    const int dvc = m & 15;
    const int b = bh >> 2, h = bh & 3;
    const int dv0 = dvc * 16;
    const int tid = threadIdx.x;
    const int kk = tid & 15;
    const int dvl = tid >> 4;

    __shared__ __align__(16) float sQ[2][GT][320];
    __shared__ __align__(16) float sK[2][GT][2][320];
    __shared__ __align__(16) float sV[2][GT][2][16];
    __shared__ float sB[2][GT][2];
    __shared__ float sG[2][GT];

    f32x2 S2[8];
#pragma unroll
    for (int j = 0; j < 8; j++) S2[j] = (f32x2){0.f, 0.f};

    const size_t bT = (size_t)b * T_;

    // staging registers (global -> reg early, reg -> LDS late)
    short4v rq0, rq1, rk00, rk01, rk10, rk11, rv0, rv1;
    float rb = 0.f, rg = 0.f;

    auto stage_load = [&](int grp) {
        const size_t t0 = bT + (size_t)grp * GT;
        {
            const int tq = tid >> 5, e = (tid & 31) * 8;
            const ushort_t* qp = q + ((t0 + tq) * 4 + h) * 256 + e;
            rq0 = *reinterpret_cast<const short4v*>(qp);
            rq1 = *reinterpret_cast<const short4v*>(qp + 4);
        }
        {
            const int idx = tid * 8;
            const int tk = idx >> 9, ii = (idx >> 8) & 1, e = idx & 255;
            const ushort_t* kp = k + (((t0 + tk) * 2 + ii) * 4 + h) * 256 + e;
            rk00 = *reinterpret_cast<const short4v*>(kp);
            rk01 = *reinterpret_cast<const short4v*>(kp + 4);
        }
        {
            const int idx = 2048 + tid * 8;
            const int tk = idx >> 9, ii = (idx >> 8) & 1, e = idx & 255;
            const ushort_t* kp = k + (((t0 + tk) * 2 + ii) * 4 + h) * 256 + e;
            rk10 = *reinterpret_cast<const short4v*>(kp);
            rk11 = *reinterpret_cast<const short4v*>(kp + 4);
        }
        if (tid < 32) {
            const int tv = tid >> 2, ii = (tid >> 1) & 1, e8 = (tid & 1) * 8;
            const ushort_t* vp = v + (((t0 + tv) * 2 + ii) * 4 + h) * 256 + dv0 + e8;
            rv0 = *reinterpret_cast<const short4v*>(vp);
            rv1 = *reinterpret_cast<const short4v*>(vp + 4);
        }
        if (tid < 16) rb = beta[(t0 + (tid >> 1)) * 8 + (tid & 1) * 4 + h];
        else if (tid < 24) rg = g[(t0 + (tid - 16)) * 4 + h];
    };

    auto stage_write = [&](int bufi) {
        {
            const int tq = tid >> 5, e = (tid & 31) * 8;
            float* dst = &sQ[bufi][tq][(e >> 4) * 20 + (e & 15)];
            *reinterpret_cast<float4*>(dst) = cvt4(rq0);
            *reinterpret_cast<float4*>(dst + 4) = cvt4(rq1);
        }
        {
            const int idx = tid * 8;
            const int tk = idx >> 9, ii = (idx >> 8) & 1, e = idx & 255;
            float* dst = &sK[bufi][tk][ii][(e >> 4) * 20 + (e & 15)];
            *reinterpret_cast<float4*>(dst) = cvt4(rk00);
            *reinterpret_cast<float4*>(dst + 4) = cvt4(rk01);
        }
        {
            const int idx = 2048 + tid * 8;
            const int tk = idx >> 9, ii = (idx >> 8) & 1, e = idx & 255;
            float* dst = &sK[bufi][tk][ii][(e >> 4) * 20 + (e & 15)];
            *reinterpret_cast<float4*>(dst) = cvt4(rk10);
            *reinterpret_cast<float4*>(dst + 4) = cvt4(rk11);
        }
        if (tid < 32) {
            const int tv = tid >> 2, ii = (tid >> 1) & 1, e8 = (tid & 1) * 8;
            float* dst = &sV[bufi][tv][ii][e8];
            *reinterpret_cast<float4*>(dst) = cvt4(rv0);
            *reinterpret_cast<float4*>(dst + 4) = cvt4(rv1);
        }
        if (tid < 16) sB[bufi][tid >> 1][tid & 1] = rb;
        else if (tid < 24) sG[bufi][tid - 16] = rg;
    };

    stage_load(0);
    stage_write(0);
    __syncthreads();
    int buf = 0;
    const int NG = T_ / GT;
    for (int grp = 0; grp < NG; ++grp) {
        if (grp + 1 < NG) stage_load(grp + 1);   // HBM latency hides under compute

        // group-start scalar prefetch (constant-indexed after unroll)
        float dec[GT], bb0[GT], bb1[GT], vv0[GT], vv1[GT];
#pragma unroll
        for (int tt = 0; tt < GT; ++tt) {
            dec[tt] = __expf(sG[buf][tt]);
            bb0[tt] = sB[buf][tt][0];
            bb1[tt] = sB[buf][tt][1];
            vv0[tt] = sV[buf][tt][0][dvl];
            vv1[tt] = sV[buf][tt][1][dvl];
        }

#pragma unroll
        for (int tt = 0; tt < GT; ++tt) {
            const float dtt = dec[tt];
            const f32x2 d2 = {dtt, dtt};
            // ---- i = 0 (decay fused) ----
            const f32x2* kp0 = reinterpret_cast<const f32x2*>(&sK[buf][tt][0][kk * 20]);
            f32x2 a0 = kp0[0], a1 = kp0[1], a2 = kp0[2], a3 = kp0[3],
                  a4 = kp0[4], a5 = kp0[5], a6 = kp0[6], a7 = kp0[7];
            f32x2 acc0 = a0 * S2[0];
            f32x2 acc1 = a1 * S2[1];
            acc0 += a2 * S2[2];  acc1 += a3 * S2[3];
            acc0 += a4 * S2[4];  acc1 += a5 * S2[5];
            acc0 += a6 * S2[6];  acc1 += a7 * S2[7];
            const f32x2 ac = acc0 + acc1;
            const float pred0 = red16(ac.x + ac.y) * dtt;
            const float u0 = (vv0[tt] - pred0) * bb0[tt];
            const f32x2 u02 = {u0, u0};
            S2[0] = S2[0] * d2 + a0 * u02;
            S2[1] = S2[1] * d2 + a1 * u02;
            S2[2] = S2[2] * d2 + a2 * u02;
            S2[3] = S2[3] * d2 + a3 * u02;
            S2[4] = S2[4] * d2 + a4 * u02;
            S2[5] = S2[5] * d2 + a5 * u02;
            S2[6] = S2[6] * d2 + a6 * u02;
            S2[7] = S2[7] * d2 + a7 * u02;
            // ---- i = 1 ----
            const f32x2* kp1 = reinterpret_cast<const f32x2*>(&sK[buf][tt][1][kk * 20]);
            f32x2 b0 = kp1[0], b1 = kp1[1], b2 = kp1[2], b3 = kp1[3],
                  b4 = kp1[4], b5 = kp1[5], b6 = kp1[6], b7 = kp1[7];
            acc0 = b0 * S2[0];
            acc1 = b1 * S2[1];
            acc0 += b2 * S2[2];  acc1 += b3 * S2[3];
            acc0 += b4 * S2[4];  acc1 += b5 * S2[5];
            acc0 += b6 * S2[6];  acc1 += b7 * S2[7];
            const f32x2 bc = acc0 + acc1;
            const float pred1 = red16(bc.x + bc.y);
            const float u1 = (vv1[tt] - pred1) * bb1[tt];
            const f32x2 u12 = {u1, u1};
            S2[0] += b0 * u12;  S2[1] += b1 * u12;
            S2[2] += b2 * u12;  S2[3] += b3 * u12;
            S2[4] += b4 * u12;  S2[5] += b5 * u12;
            S2[6] += b6 * u12;  S2[7] += b7 * u12;
            // ---- output ----
            const f32x2* qp = reinterpret_cast<const f32x2*>(&sQ[buf][tt][kk * 20]);
            acc0 = qp[0] * S2[0];
            acc1 = qp[1] * S2[1];
            acc0 += qp[2] * S2[2];  acc1 += qp[3] * S2[3];
            acc0 += qp[4] * S2[4];  acc1 += qp[5] * S2[5];
            acc0 += qp[6] * S2[6];  acc1 += qp[7] * S2[7];
            const f32x2 qc = acc0 + acc1;
            const float op = red16(qc.x + qc.y);
            if (kk == 0)
                o[((bT + (size_t)grp * GT + tt) * 4 + h) * 256 + dv0 + dvl] = f2bf(op * 0.0625f);
        }
        if (grp + 1 < NG) stage_write(buf ^ 1);  // after compute: loads landed
        __syncthreads();
        buf ^= 1;
    }
}

// silu(g)*u on bf16, in-place into g buffer (4 elems per thread)
__global__ __launch_bounds__(256)
void silu_mul_kernel(ushort_t* __restrict__ gb, const ushort_t* __restrict__ ub)
{
    const size_t i = (size_t)blockIdx.x * 256 + threadIdx.x;
    const float4 gv = cvt4(reinterpret_cast<short4v*>(gb)[i]);
    const float4 uv = cvt4(reinterpret_cast<const short4v*>(ub)[i]);
    float4 r;
    r.x = siluf_(gv.x) * uv.x; r.y = siluf_(gv.y) * uv.y;
    r.z = siluf_(gv.z) * uv.z; r.w = siluf_(gv.w) * uv.w;
    reinterpret_cast<short4v*>(gb)[i] = pack4(r);
}

// copy out[:, T-1, :] to tail of d_out
__global__ __launch_bounds__(256)
void tail_kernel(float* __restrict__ out)
{
    const int i = blockIdx.x * 256 + threadIdx.x;
    const int b = i >> 10, d = i & 1023;
    out[(size_t)B_ * T_ * D_ + i] = out[((size_t)b * T_ + (T_ - 1)) * D_ + d];
}

// ---------------------------------------------------------------------------
extern "C" void kernel_launch(void* const* d_in, const int* in_sizes, int n_in,
                              void* d_out, int out_size, void* d_ws, size_t ws_size,
                              hipStream_t stream)
{
    const float* x    = (const float*)d_in[0];
    const float* prev = (const float*)d_in[1];
    const float* spw  = (const float*)d_in[2];
    const float* sgw  = (const float*)d_in[3];
    const float* sgb  = (const float*)d_in[4];
    const float* anw  = (const float*)d_in[5];
    const float* qw   = (const float*)d_in[6];
    const float* kw   = (const float*)d_in[7];
    const float* vw   = (const float*)d_in[8];
    const float* bw   = (const float*)d_in[9];
    const float* aw   = (const float*)d_in[10];
    const float* Alog = (const float*)d_in[11];
    const float* dtb  = (const float*)d_in[12];
    const float* qcw  = (const float*)d_in[13];
    const float* kcw  = (const float*)d_in[14];
    const float* vcw  = (const float*)d_in[15];
    const float* onw  = (const float*)d_in[16];
    const float* ow   = (const float*)d_in[17];
    const float* mnw  = (const float*)d_in[18];
    const float* gw   = (const float*)d_in[19];
    const float* uw   = (const float*)d_in[20];
    const float* dw   = (const float*)d_in[21];
    float* out = (float*)d_out;

    const size_t NX = (size_t)B_ * T_ * D_;   // 16,777,216
    const int M = B_ * T_;                    // 16384
    const size_t MI = (size_t)M * I_;         // 46,137,344

    // ---- workspace layout (shorts), peak ~242 MB ----
    ushort_t* wsb = (ushort_t*)d_ws;
    size_t off = 0;
    ushort_t* wsc = wsb + off; off += 2883584;   // weight scratch (max I_*D_)
    ushort_t* hb  = wsb + off; off += NX;        // hb / onb / h2b
    ushort_t* raw = wsb + off; off += NX;        // pre-conv chunk; later ob
    ushort_t* qb  = wsb + off; off += NX;
    ushort_t* kb  = wsb + off; off += 2 * NX;    // also hosts xb early
    ushort_t* vb  = wsb + off; off += 2 * NX;
    float*    es   = (float*)(wsb + off);
    float*    esg  = es + (size_t)B_ * D_;
    float*    beta = esg + (size_t)B_ * D_;
    float*    gbuf = beta + (size_t)M * 8;
    // overlays
    ushort_t* xb  = kb;        // bf16(x) for gate GEMM (dead before conv fills kb)
    ushort_t* ob  = raw;       // scan output (raw dead after convs)
    ushort_t* mgb = raw;       // MLP: MI shorts over raw+qb+kb (dead post-scan)
    ushort_t* mub = raw + MI;  // MI shorts, ends within vb
    float*    xf  = out;       // f32 residual stream lives in d_out

    // ---- state fusion ----
    tobf16_kernel<<<(int)(NX / 1024), 256, 0, stream>>>(x, xb);
    tobf16_kernel<<<2048, 256, 0, stream>>>(sgw, wsc);
    es_kernel<<<2048, 256, 0, stream>>>(prev, spw, es);
    esg_kernel<<<2048, 256, 0, stream>>>(es, sgw, sgb, esg);
    gemm_bf16<2><<<dim3(8, 128), 256, 0, stream>>>(
        xb, D_, wsc, 2 * D_, xf, nullptr, M, D_, D_, x, es, esg);

    // ---- attention sub-block ----
    rmsnorm_bf16_kernel<<<M, 256, 0, stream>>>(xf, anw, hb);
    proj_ba_kernel<<<M, 256, 0, stream>>>(hb, bw, aw, Alog, dtb, beta, gbuf);

    // q: one N=1024 chunk
    tobf16_kernel<<<1024, 256, 0, stream>>>(qw, wsc);
    gemm_bf16<0><<<dim3(8, 128), 256, 0, stream>>>(
        hb, D_, wsc, D_, nullptr, raw, M, 1024, D_, nullptr, nullptr, nullptr);
    conv_silu_kernel<<<16384, 256, 0, stream>>>(raw, qcw, qb, 256, 256, 0, 0);

    // k: two N=1024 chunks
    tobf16_kernel<<<2048, 256, 0, stream>>>(kw, wsc);
    for (int j = 0; j < 2; j++) {
        gemm_bf16<0><<<dim3(8, 128), 256, 0, stream>>>(
            hb, D_, wsc + (size_t)j * 1024 * D_, D_, nullptr, raw, M, 1024, D_,
            nullptr, nullptr, nullptr);
        conv_silu_kernel<<<16384, 256, 0, stream>>>(raw, kcw, kb, 256, 512, j * 256, j * 1024);
    }

    // v: two N=1024 chunks
    tobf16_kernel<<<2048, 256, 0, stream>>>(vw, wsc);
    for (int j = 0; j < 2; j++) {
        gemm_bf16<0><<<dim3(8, 128), 256, 0, stream>>>(
            hb, D_, wsc + (size_t)j * 1024 * D_, D_, nullptr, raw, M, 1024, D_,
            nullptr, nullptr, nullptr);
        conv_silu_kernel<<<16384, 256, 0, stream>>>(raw, vcw, vb, 256, 512, j * 256, j * 1024);
    }

    l2n_kernel<<<16384, 256, 0, stream>>>(qb);
    l2n_kernel<<<32768, 256, 0, stream>>>(kb);

    scan_kernel<<<512, 256, 0, stream>>>(qb, kb, vb, beta, gbuf, ob);

    onorm_bf16_kernel<<<16384, 256, 0, stream>>>(ob, onw, hb);
    tobf16_kernel<<<1024, 256, 0, stream>>>(ow, wsc);
    gemm_bf16<1><<<dim3(8, 128), 256, 0, stream>>>(
        hb, D_, wsc, D_, out, nullptr, M, 1024, D_, xf, nullptr, nullptr);

    // ---- MLP sub-block ----
    rmsnorm_bf16_kernel<<<M, 256, 0, stream>>>(out, mnw, hb);
    tobf16_kernel<<<2816, 256, 0, stream>>>(gw, wsc);
    gemm_bf16<0><<<dim3(22, 128), 256, 0, stream>>>(
        hb, D_, wsc, D_, nullptr, mgb, M, I_, D_, nullptr, nullptr, nullptr);
    tobf16_kernel<<<2816, 256, 0, stream>>>(uw, wsc);
    gemm_bf16<0><<<dim3(22, 128), 256, 0, stream>>>(
        hb, D_, wsc, D_, nullptr, mub, M, I_, D_, nullptr, nullptr, nullptr);
    silu_mul_kernel<<<(int)((MI / 4) / 256), 256, 0, stream>>>(mgb, mub);
    tobf16_kernel<<<2816, 256, 0, stream>>>(dw, wsc);
    gemm_bf16<1><<<dim3(8, 128), 256, 0, stream>>>(
        mgb, I_, wsc, I_, out, nullptr, M, 1024, I_, out, nullptr, nullptr);

    tail_kernel<<<32, 256, 0, stream>>>(out);
}